// Round 10
// baseline (94.073 us; speedup 1.0000x reference)
//
#include <hip/hip_runtime.h>
#include <hip/hip_bf16.h>

#define B_ 8192
#define F_ 1024
#define P_ 160
#define C_ 10

typedef __attribute__((ext_vector_type(8))) short short8;
typedef __attribute__((ext_vector_type(4))) float f32x4;
typedef unsigned short ushort_t;

// ---- helpers -------------------------------------------------------------

__device__ inline unsigned pk2(float a, float b) {
    __hip_bfloat162 h = __float22bfloat162_rn(make_float2(a, b));
    return *reinterpret_cast<unsigned*>(&h);
}
__device__ inline float lo_f(unsigned u) { return __uint_as_float(u << 16); }
__device__ inline float hi_f(unsigned u) { return __uint_as_float(u & 0xffff0000u); }
__device__ inline float bf_f(short s) {
    return __uint_as_float(((unsigned)(unsigned short)s) << 16);
}

__device__ inline void gload16(const void* g, void* l) {
    __builtin_amdgcn_global_load_lds((const __attribute__((address_space(1))) unsigned*)g,
                                     (__attribute__((address_space(3))) unsigned*)l, 16, 0, 0);
}

// ---- k_prep1: conversions + zero + zp GEMM, one launch -------------------
// blocks 0..255: om tiles; 256..265: prot split (mode!=2 only);
// 266: zero sqx+sqp; 267..4362: x -> swizzled bf16; 4363..4522: zp direct.
__global__ __launch_bounds__(256)
void k_prep1(const float* __restrict__ om, const float* __restrict__ prot,
             const float* __restrict__ x,
             ushort_t* __restrict__ omh_r, ushort_t* __restrict__ oml_r,
             ushort_t* __restrict__ omTh, ushort_t* __restrict__ omTl,
             ushort_t* __restrict__ omh_sw,
             ushort_t* __restrict__ phl, ushort_t* __restrict__ pll,
             ushort_t* __restrict__ xh, float4* __restrict__ zero_dst,
             ushort_t* __restrict__ zph, ushort_t* __restrict__ zpl,
             int mode) {
    const int bid = blockIdx.x, tid = threadIdx.x;
    if (bid < 256) {
        const int tr = bid >> 4, tc = bid & 15;
        __shared__ float tile[64][65];
        const int r0 = tid >> 4, cq = (tid & 15) * 4;
#pragma unroll
        for (int i = 0; i < 4; ++i) {
            const int row = r0 + i * 16;
            const int gr = tr * 64 + row;
            float4 v = *reinterpret_cast<const float4*>(om + (size_t)gr * F_ + tc * 64 + cq);
            tile[row][cq + 0] = v.x; tile[row][cq + 1] = v.y;
            tile[row][cq + 2] = v.z; tile[row][cq + 3] = v.w;
            unsigned h0 = pk2(v.x, v.y), h1 = pk2(v.z, v.w);
            if (mode != 2) {
                unsigned l0 = pk2(v.x - lo_f(h0), v.y - hi_f(h0));
                unsigned l1 = pk2(v.z - lo_f(h1), v.w - hi_f(h1));
                size_t ro = (size_t)gr * F_ + tc * 64 + cq;
                *reinterpret_cast<uint2*>(omh_r + ro) = make_uint2(h0, h1);
                *reinterpret_cast<uint2*>(oml_r + ro) = make_uint2(l0, l1);
            }
            const int rb = gr >> 7, r = gr & 127;
            const int c0 = tc * 64 + cq;
            const int t32 = c0 >> 5, k8 = (c0 >> 3) & 3, half = (c0 >> 2) & 1;
            size_t base = ((size_t)(rb * 32 + t32)) * 8192;
            int off = (r * 64 + k8 * 16) ^ ((r & 7) << 4);
            *reinterpret_cast<uint2*>(reinterpret_cast<char*>(omh_sw) + base + off + half * 8) =
                make_uint2(h0, h1);
        }
        __syncthreads();
#pragma unroll
        for (int i = 0; i < 4; ++i) {
            const int rowT = r0 + i * 16;
            float a = tile[cq + 0][rowT], b = tile[cq + 1][rowT];
            float c = tile[cq + 2][rowT], d = tile[cq + 3][rowT];
            unsigned h0 = pk2(a, b), h1 = pk2(c, d);
            unsigned l0 = pk2(a - lo_f(h0), b - hi_f(h0));
            unsigned l1 = pk2(c - lo_f(h1), d - hi_f(h1));
            size_t to = (size_t)(tc * 64 + rowT) * F_ + tr * 64 + cq;
            *reinterpret_cast<uint2*>(omTh + to) = make_uint2(h0, h1);
            *reinterpret_cast<uint2*>(omTl + to) = make_uint2(l0, l1);
        }
    } else if (bid < 266) {
        if (mode != 2) {
            const int pb = bid - 256;
            const int row = pb * 16 + (tid >> 4);
#pragma unroll
            for (int i = 0; i < 16; ++i) {
                const int col = (tid & 15) * 4 + i * 64;
                float4 v = *reinterpret_cast<const float4*>(prot + (size_t)row * F_ + col);
                unsigned h0 = pk2(v.x, v.y), h1 = pk2(v.z, v.w);
                unsigned l0 = pk2(v.x - lo_f(h0), v.y - hi_f(h0));
                unsigned l1 = pk2(v.z - lo_f(h1), v.w - hi_f(h1));
                size_t ro = (size_t)row * F_ + col;
                *reinterpret_cast<uint2*>(phl + ro) = make_uint2(h0, h1);
                *reinterpret_cast<uint2*>(pll + ro) = make_uint2(l0, l1);
            }
        }
    } else if (bid == 266) {
        const float4 z = make_float4(0.f, 0.f, 0.f, 0.f);
        for (int i = tid; i < 2112; i += 256) zero_dst[i] = z;
    } else if (bid < 4363) {
        const int c = (bid - 267) * 256 + tid;
        const int rg = c >> 7, kg = c & 127;
        const int t = kg >> 2, k8 = kg & 3;
        const float4* s4 = reinterpret_cast<const float4*>(x + (size_t)rg * F_ + t * 32 + k8 * 8);
        float4 v0 = s4[0], v1 = s4[1];
        uint4 o;
        o.x = pk2(v0.x, v0.y); o.y = pk2(v0.z, v0.w);
        o.z = pk2(v1.x, v1.y); o.w = pk2(v1.z, v1.w);
        const int rb = rg >> 7, r = rg & 127;
        size_t base = ((size_t)(rb * 32 + t)) * 8192;
        int off = (r * 64 + k8 * 16) ^ ((r & 7) << 4);
        *reinterpret_cast<uint4*>(reinterpret_cast<char*>(xh) + base + off) = o;
    } else {
        // zp = prot @ om^T directly from f32 (inline hi/lo split, 3-term)
        const int fid = (bid - 4363) * 4 + (tid >> 6);
        const int m = fid >> 6, n = fid & 63;
        const int lane = tid & 63, l15v = lane & 15, gv = lane >> 4;
        f32x4 acc = {};
        const float* pa = prot + (size_t)(m * 16 + l15v) * F_ + gv * 8;
        const float* pb = om   + (size_t)(n * 16 + l15v) * F_ + gv * 8;
#pragma unroll 2
        for (int ks = 0; ks < 32; ++ks) {
            float4 a0 = *reinterpret_cast<const float4*>(pa + ks * 32);
            float4 a1 = *reinterpret_cast<const float4*>(pa + ks * 32 + 4);
            float4 b0 = *reinterpret_cast<const float4*>(pb + ks * 32);
            float4 b1 = *reinterpret_cast<const float4*>(pb + ks * 32 + 4);
            union { unsigned u[4]; short8 s; } cah, cal, cbh, cbl;
            cah.u[0] = pk2(a0.x, a0.y); cah.u[1] = pk2(a0.z, a0.w);
            cah.u[2] = pk2(a1.x, a1.y); cah.u[3] = pk2(a1.z, a1.w);
            cal.u[0] = pk2(a0.x - lo_f(cah.u[0]), a0.y - hi_f(cah.u[0]));
            cal.u[1] = pk2(a0.z - lo_f(cah.u[1]), a0.w - hi_f(cah.u[1]));
            cal.u[2] = pk2(a1.x - lo_f(cah.u[2]), a1.y - hi_f(cah.u[2]));
            cal.u[3] = pk2(a1.z - lo_f(cah.u[3]), a1.w - hi_f(cah.u[3]));
            cbh.u[0] = pk2(b0.x, b0.y); cbh.u[1] = pk2(b0.z, b0.w);
            cbh.u[2] = pk2(b1.x, b1.y); cbh.u[3] = pk2(b1.z, b1.w);
            cbl.u[0] = pk2(b0.x - lo_f(cbh.u[0]), b0.y - hi_f(cbh.u[0]));
            cbl.u[1] = pk2(b0.z - lo_f(cbh.u[1]), b0.w - hi_f(cbh.u[1]));
            cbl.u[2] = pk2(b1.x - lo_f(cbh.u[2]), b1.y - hi_f(cbh.u[2]));
            cbl.u[3] = pk2(b1.z - lo_f(cbh.u[3]), b1.w - hi_f(cbh.u[3]));
            acc = __builtin_amdgcn_mfma_f32_16x16x32_bf16(cah.s, cbh.s, acc, 0, 0, 0);
            acc = __builtin_amdgcn_mfma_f32_16x16x32_bf16(cal.s, cbh.s, acc, 0, 0, 0);
            acc = __builtin_amdgcn_mfma_f32_16x16x32_bf16(cah.s, cbl.s, acc, 0, 0, 0);
        }
#pragma unroll
        for (int j = 0; j < 4; ++j) {
            float v = acc[j];
            const int row = m * 16 + gv * 4 + j, col = n * 16 + l15v;
            unsigned hv = pk2(v, 0.f);
            unsigned lv = pk2(v - lo_f(hv), 0.f);
            zph[(size_t)row * F_ + col] = (ushort_t)hv;
            zpl[(size_t)row * F_ + col] = (ushort_t)lv;
        }
    }
}

// ---- k_zp2: tier-1 only (unchanged) --------------------------------------
__global__ __launch_bounds__(256)
void k_zp2(const ushort_t* __restrict__ phl, const ushort_t* __restrict__ pll,
           const ushort_t* __restrict__ omh_r, const ushort_t* __restrict__ oml_r,
           ushort_t* __restrict__ zph, ushort_t* __restrict__ zpl,
           float* __restrict__ sqp) {
    const int tid = threadIdx.x, lane = tid & 63, w = tid >> 6;
    const int fid = blockIdx.x * 4 + w;
    const int m = fid >> 6, n = fid & 63;
    const int l15 = lane & 15, g = lane >> 4;

    f32x4 acc = {};
    const ushort_t* pa_h = phl + (size_t)(m * 16 + l15) * F_ + g * 8;
    const ushort_t* pa_l = pll + (size_t)(m * 16 + l15) * F_ + g * 8;
    const ushort_t* pb_h = omh_r + (size_t)(n * 16 + l15) * F_ + g * 8;
    const ushort_t* pb_l = oml_r + (size_t)(n * 16 + l15) * F_ + g * 8;
#pragma unroll 4
    for (int ks = 0; ks < 32; ++ks) {
        short8 ah = *reinterpret_cast<const short8*>(pa_h + ks * 32);
        short8 al = *reinterpret_cast<const short8*>(pa_l + ks * 32);
        short8 bh = *reinterpret_cast<const short8*>(pb_h + ks * 32);
        short8 bl = *reinterpret_cast<const short8*>(pb_l + ks * 32);
        acc = __builtin_amdgcn_mfma_f32_16x16x32_bf16(ah, bh, acc, 0, 0, 0);
        acc = __builtin_amdgcn_mfma_f32_16x16x32_bf16(al, bh, acc, 0, 0, 0);
        acc = __builtin_amdgcn_mfma_f32_16x16x32_bf16(ah, bl, acc, 0, 0, 0);
    }
#pragma unroll
    for (int j = 0; j < 4; ++j) {
        float v = acc[j];
        const int row = m * 16 + g * 4 + j, col = n * 16 + l15;
        unsigned hv = pk2(v, 0.f);
        unsigned lv = pk2(v - lo_f(hv), 0.f);
        zph[(size_t)row * F_ + col] = (ushort_t)hv;
        zpl[(size_t)row * F_ + col] = (ushort_t)lv;
        float s = v * v;
        s += __shfl_xor(s, 1); s += __shfl_xor(s, 2);
        s += __shfl_xor(s, 4); s += __shfl_xor(s, 8);
        if (l15 == 0) atomicAdd(&sqp[row], s);
    }
}

// ---- k_u2z: fused {u = zp @ om, + sqp} + {sq_x GEMM} ---------------------
__global__ __launch_bounds__(256)
void k_u2z(const ushort_t* __restrict__ zph, const ushort_t* __restrict__ zpl,
           const ushort_t* __restrict__ omTh, const ushort_t* __restrict__ omTl,
           ushort_t* __restrict__ uh, ushort_t* __restrict__ up,
           const ushort_t* __restrict__ xh, const ushort_t* __restrict__ omh_sw,
           float* __restrict__ sqx, float* __restrict__ sqp) {
    __shared__ __align__(16) ushort_t sA[128 * 32];
    __shared__ __align__(16) ushort_t sB[128 * 32];
    const int tid = threadIdx.x;
    const int lane = tid & 63, w = tid >> 6;
    const int l15 = lane & 15, g = lane >> 4;

    if (blockIdx.x < 160) {
        const int fid = blockIdx.x * 4 + w;
        const int m = fid >> 6, n = fid & 63;
        f32x4 acc = {};
        float sq = 0.f;
        const ushort_t* pa_h = zph + (size_t)(m * 16 + l15) * F_ + g * 8;
        const ushort_t* pa_l = zpl + (size_t)(m * 16 + l15) * F_ + g * 8;
        const ushort_t* pb_h = omTh + (size_t)(n * 16 + l15) * F_ + g * 8;
        const ushort_t* pb_l = omTl + (size_t)(n * 16 + l15) * F_ + g * 8;
#pragma unroll 4
        for (int ks = 0; ks < 32; ++ks) {
            short8 ah = *reinterpret_cast<const short8*>(pa_h + ks * 32);
            short8 al = *reinterpret_cast<const short8*>(pa_l + ks * 32);
            short8 bh = *reinterpret_cast<const short8*>(pb_h + ks * 32);
            short8 bl = *reinterpret_cast<const short8*>(pb_l + ks * 32);
            acc = __builtin_amdgcn_mfma_f32_16x16x32_bf16(ah, bh, acc, 0, 0, 0);
            acc = __builtin_amdgcn_mfma_f32_16x16x32_bf16(al, bh, acc, 0, 0, 0);
            acc = __builtin_amdgcn_mfma_f32_16x16x32_bf16(ah, bl, acc, 0, 0, 0);
            if (n == 0) {   // wave-uniform: these 10 waves also reduce sqp
#pragma unroll
                for (int e = 0; e < 8; ++e) {
                    float v = bf_f(ah[e]) + bf_f(al[e]);
                    sq = fmaf(v, v, sq);
                }
            }
        }
        if (n == 0) {
            sq += __shfl_xor(sq, 16);
            sq += __shfl_xor(sq, 32);
            if (lane < 16) sqp[m * 16 + lane] = sq;   // plain store, no atomics
        }
#pragma unroll
        for (int j = 0; j < 4; ++j) {
            float v = acc[j];
            const int rr = g * 4 + j;
            const int row = m * 16 + rr, col = n * 16 + l15;
            unsigned hv = pk2(v, 0.f);
            ushort_t hs = (ushort_t)hv;
            uh[(size_t)row * F_ + col] = hs;
            const int ks = col >> 5, gg = (col >> 3) & 3, e = col & 7;
            up[(((size_t)m * 32 + ks) * 64 + gg * 16 + rr) * 8 + e] = hs;
        }
    } else {
        const int zb = blockIdx.x - 160;
        const int bx = zb & 63, by = zb >> 6;
        const int wr = (w >> 1) * 64, wc = (w & 1) * 64;
        f32x4 acc[4][4] = {};
        const char* xb = reinterpret_cast<const char*>(xh) + (size_t)bx * 32 * 8192;
        const char* ob = reinterpret_cast<const char*>(omh_sw) + (size_t)by * 32 * 8192;
        char* sAc = reinterpret_cast<char*>(sA);
        char* sBc = reinterpret_cast<char*>(sB);
        for (int t = 0; t < 32; ++t) {
            __syncthreads();
            gload16(xb + (size_t)t * 8192 + tid * 16,        sAc + tid * 16);
            gload16(xb + (size_t)t * 8192 + 4096 + tid * 16, sAc + 4096 + tid * 16);
            gload16(ob + (size_t)t * 8192 + tid * 16,        sBc + tid * 16);
            gload16(ob + (size_t)t * 8192 + 4096 + tid * 16, sBc + 4096 + tid * 16);
            __syncthreads();
            short8 a[4], b[4];
#pragma unroll
            for (int m = 0; m < 4; ++m) {
                int row = wr + m * 16 + l15;
                int off = (row * 64 + g * 16) ^ ((row & 7) << 4);
                a[m] = *reinterpret_cast<const short8*>(sAc + off);
            }
#pragma unroll
            for (int n = 0; n < 4; ++n) {
                int row = wc + n * 16 + l15;
                int off = (row * 64 + g * 16) ^ ((row & 7) << 4);
                b[n] = *reinterpret_cast<const short8*>(sBc + off);
            }
#pragma unroll
            for (int m = 0; m < 4; ++m)
#pragma unroll
                for (int n = 0; n < 4; ++n)
                    acc[m][n] = __builtin_amdgcn_mfma_f32_16x16x32_bf16(a[m], b[n], acc[m][n], 0, 0, 0);
        }
#pragma unroll
        for (int m = 0; m < 4; ++m) {
#pragma unroll
            for (int j = 0; j < 4; ++j) {
                float s = 0.f;
#pragma unroll
                for (int n = 0; n < 4; ++n) { float v = acc[m][n][j]; s = fmaf(v, v, s); }
                s += __shfl_xor(s, 1); s += __shfl_xor(s, 2);
                s += __shfl_xor(s, 4); s += __shfl_xor(s, 8);
                if (l15 == 0) atomicAdd(&sqx[bx * 128 + wr + m * 16 + g * 4 + j], s);
            }
        }
    }
}

// ---- k_dist5 (R7 verbatim): M-tile 16, 8 waves (K-quarter x N-half) ------
__global__ __launch_bounds__(512)
void k_dist5(const ushort_t* __restrict__ xh, const ushort_t* __restrict__ up,
             const float* __restrict__ sqx, const float* __restrict__ sqp,
             float* __restrict__ dist, float* __restrict__ pred) {
    const int brow = blockIdx.x * 16;
    const int tid = threadIdx.x, lane = tid & 63, w = tid >> 6;
    const int wk = w & 3, nh = w >> 2;
    const int l15 = lane & 15, g = lane >> 4;
    __shared__ float red[4][10][16][16];
    __shared__ float cminv[16][2];
    __shared__ int   cmini[16][2];

    f32x4 acc[5] = {};
    const int rb = brow >> 7, r = (brow & 127) + l15;
    const char* xb = reinterpret_cast<const char*>(xh) +
                     ((size_t)(rb * 32 + wk * 8)) * 8192 +
                     (((r * 64 + g * 16)) ^ ((r & 7) << 4));

#pragma unroll
    for (int ksl = 0; ksl < 8; ++ksl) {
        short8 ah = *reinterpret_cast<const short8*>(xb + (size_t)ksl * 8192);
#pragma unroll
        for (int f = 0; f < 5; ++f) {
            const int fg = nh * 5 + f;
            short8 bh = *reinterpret_cast<const short8*>(
                up + (((size_t)fg * 32 + wk * 8 + ksl) * 64 + lane) * 8);
            acc[f] = __builtin_amdgcn_mfma_f32_16x16x32_bf16(ah, bh, acc[f], 0, 0, 0);
        }
    }

#pragma unroll
    for (int f = 0; f < 5; ++f)
#pragma unroll
        for (int j = 0; j < 4; ++j)
            red[wk][nh * 5 + f][g * 4 + j][l15 ^ g] = acc[f][j];
    __syncthreads();

    const int fh = tid >> 8, m = (tid >> 4) & 15, n = tid & 15;
    const int row = brow + m;
    const int nn = n ^ (m >> 2);
    const float sx = sqx[row];
    float best = 3.4e38f; int bi = 0;
#pragma unroll
    for (int f = 0; f < 5; ++f) {
        const int fg = fh * 5 + f;
        float d = red[0][fg][m][nn] + red[1][fg][m][nn] +
                  red[2][fg][m][nn] + red[3][fg][m][nn];
        float dv = sx + sqp[fg * 16 + n] - 2.f * d;
        dist[(size_t)row * P_ + fg * 16 + n] = dv;
        float mn = dv;
        mn = fminf(mn, __shfl_xor(mn, 1));
        mn = fminf(mn, __shfl_xor(mn, 2));
        mn = fminf(mn, __shfl_xor(mn, 4));
        mn = fminf(mn, __shfl_xor(mn, 8));
        if (mn < best) { best = mn; bi = fg; }   // strict '<' => first min
    }
    if (n == 0) { cminv[m][fh] = best; cmini[m][fh] = bi; }
    __syncthreads();
    if (tid < 16) {
        float v0 = cminv[tid][0], v1 = cminv[tid][1];
        pred[brow + tid] = (float)((v1 < v0) ? cmini[tid][1] : cmini[tid][0]);
    }
}

// ---- tier-1 fallbacks ----------------------------------------------------

__global__ __launch_bounds__(256)
void k_z_sqx(const float* __restrict__ x, const float* __restrict__ om,
             float* __restrict__ sqx) {
    const int brow = blockIdx.x * 128;
    const int bcol = blockIdx.y * 128;
    __shared__ __align__(16) ushort_t sA[128 * 32];
    __shared__ __align__(16) ushort_t sB[128 * 32];
    const int tid = threadIdx.x;
    const int lane = tid & 63, w = tid >> 6;
    const int wr = (w >> 1) * 64, wc = (w & 1) * 64;
    const int l15 = lane & 15, g = lane >> 4;
    f32x4 acc[4][4] = {};
    for (int k0 = 0; k0 < F_; k0 += 32) {
        __syncthreads();
#pragma unroll
        for (int j = 0; j < 4; ++j) {
            int idx = tid + j * 256;
            int row = idx >> 3, c4 = idx & 7;
            float4 va = *reinterpret_cast<const float4*>(x  + (size_t)(brow + row) * F_ + k0 + c4 * 4);
            float4 vb = *reinterpret_cast<const float4*>(om + (size_t)(bcol + row) * F_ + k0 + c4 * 4);
            int off = (row * 64 + c4 * 8) ^ ((row & 7) << 4);
            *reinterpret_cast<uint2*>(reinterpret_cast<char*>(sA) + off) =
                make_uint2(pk2(va.x, va.y), pk2(va.z, va.w));
            *reinterpret_cast<uint2*>(reinterpret_cast<char*>(sB) + off) =
                make_uint2(pk2(vb.x, vb.y), pk2(vb.z, vb.w));
        }
        __syncthreads();
        short8 a[4], b[4];
#pragma unroll
        for (int m = 0; m < 4; ++m) {
            int row = wr + m * 16 + l15;
            int off = (row * 64 + g * 16) ^ ((row & 7) << 4);
            a[m] = *reinterpret_cast<const short8*>(reinterpret_cast<const char*>(sA) + off);
        }
#pragma unroll
        for (int n = 0; n < 4; ++n) {
            int row = wc + n * 16 + l15;
            int off = (row * 64 + g * 16) ^ ((row & 7) << 4);
            b[n] = *reinterpret_cast<const short8*>(reinterpret_cast<const char*>(sB) + off);
        }
#pragma unroll
        for (int m = 0; m < 4; ++m)
#pragma unroll
            for (int n = 0; n < 4; ++n)
                acc[m][n] = __builtin_amdgcn_mfma_f32_16x16x32_bf16(a[m], b[n], acc[m][n], 0, 0, 0);
    }
#pragma unroll
    for (int m = 0; m < 4; ++m) {
#pragma unroll
        for (int j = 0; j < 4; ++j) {
            float s = 0.f;
#pragma unroll
            for (int n = 0; n < 4; ++n) { float v = acc[m][n][j]; s = fmaf(v, v, s); }
            s += __shfl_xor(s, 1); s += __shfl_xor(s, 2);
            s += __shfl_xor(s, 4); s += __shfl_xor(s, 8);
            if (l15 == 0) atomicAdd(&sqx[brow + wr + m * 16 + g * 4 + j], s);
        }
    }
}

__global__ __launch_bounds__(256)
void k_dist2(const float* __restrict__ x, const ushort_t* __restrict__ uh,
             const float* __restrict__ sqx, const float* __restrict__ sqp,
             float* __restrict__ dist, float* __restrict__ pred) {
    const int brow = blockIdx.x * 16;
    const int tid = threadIdx.x, lane = tid & 63, w = tid >> 6;
    const int l15 = lane & 15, g = lane >> 4;
    __shared__ float red[4][10][16][16];

    f32x4 acc[10] = {};
    const float* xp = x + (size_t)(brow + l15) * F_ + w * 256 + g * 8;
    const ushort_t* buh = uh + (size_t)l15 * F_ + w * 256 + g * 8;

#pragma unroll 2
    for (int ks = 0; ks < 8; ++ks) {
        float4 v0 = *reinterpret_cast<const float4*>(xp + ks * 32);
        float4 v1 = *reinterpret_cast<const float4*>(xp + ks * 32 + 4);
        union { unsigned u[4]; short8 s; } cva;
        cva.u[0] = pk2(v0.x, v0.y); cva.u[1] = pk2(v0.z, v0.w);
        cva.u[2] = pk2(v1.x, v1.y); cva.u[3] = pk2(v1.z, v1.w);
        short8 ah = cva.s;
#pragma unroll
        for (int f = 0; f < 10; ++f) {
            short8 bh = *reinterpret_cast<const short8*>(buh + (size_t)f * 16 * F_ + ks * 32);
            acc[f] = __builtin_amdgcn_mfma_f32_16x16x32_bf16(ah, bh, acc[f], 0, 0, 0);
        }
    }
#pragma unroll
    for (int f = 0; f < 10; ++f)
#pragma unroll
        for (int j = 0; j < 4; ++j) red[w][f][g * 4 + j][l15 ^ g] = acc[f][j];
    __syncthreads();
    const int m = tid >> 4, n = tid & 15;
    const int row = brow + m;
    const int nn = n ^ (m >> 2);
    float sx = sqx[row];
    float best = 3.4e38f; int bi = 0;
#pragma unroll
    for (int f = 0; f < 10; ++f) {
        float d = red[0][f][m][nn] + red[1][f][m][nn] + red[2][f][m][nn] + red[3][f][m][nn];
        float dv = sx + sqp[f * 16 + n] - 2.f * d;
        dist[(size_t)row * P_ + f * 16 + n] = dv;
        float mn = dv;
        mn = fminf(mn, __shfl_xor(mn, 1));
        mn = fminf(mn, __shfl_xor(mn, 2));
        mn = fminf(mn, __shfl_xor(mn, 4));
        mn = fminf(mn, __shfl_xor(mn, 8));
        if (mn < best) { best = mn; bi = f; }
    }
    if (n == 0) pred[row] = (float)bi;
}

// ---- tier-0 fallback kernels (R3 path) -----------------------------------

__global__ __launch_bounds__(256)
void k_proj(const float* __restrict__ prot, const float* __restrict__ om,
            float* __restrict__ zp, float* __restrict__ sqp) {
    const int n0 = blockIdx.x * 16;
    const int tid = threadIdx.x, lane = tid & 63, w = tid >> 6;
    const int l15 = lane & 15, g = lane >> 4;
    __shared__ float red[4][10][16][16];
    f32x4 acc[10] = {};
    const float* op = om   + (size_t)(n0 + l15) * F_ + w * 256 + g * 8;
    const float* pp = prot + (size_t)l15 * F_ + w * 256 + g * 8;
#pragma unroll 2
    for (int ks = 0; ks < 8; ++ks) {
        float4 b0 = *reinterpret_cast<const float4*>(op + ks * 32);
        float4 b1 = *reinterpret_cast<const float4*>(op + ks * 32 + 4);
        union { unsigned u[4]; short8 s; } cbh, cbl;
        cbh.u[0] = pk2(b0.x, b0.y); cbh.u[1] = pk2(b0.z, b0.w);
        cbh.u[2] = pk2(b1.x, b1.y); cbh.u[3] = pk2(b1.z, b1.w);
        cbl.u[0] = pk2(b0.x - lo_f(cbh.u[0]), b0.y - hi_f(cbh.u[0]));
        cbl.u[1] = pk2(b0.z - lo_f(cbh.u[1]), b0.w - hi_f(cbh.u[1]));
        cbl.u[2] = pk2(b1.x - lo_f(cbh.u[2]), b1.y - hi_f(cbh.u[2]));
        cbl.u[3] = pk2(b1.z - lo_f(cbh.u[3]), b1.w - hi_f(cbh.u[3]));
        short8 bh = cbh.s, bl = cbl.s;
#pragma unroll
        for (int f = 0; f < 10; ++f) {
            float4 a0 = *reinterpret_cast<const float4*>(pp + (size_t)f * 16 * F_ + ks * 32);
            float4 a1 = *reinterpret_cast<const float4*>(pp + (size_t)f * 16 * F_ + ks * 32 + 4);
            union { unsigned u[4]; short8 s; } cah, cal;
            cah.u[0] = pk2(a0.x, a0.y); cah.u[1] = pk2(a0.z, a0.w);
            cah.u[2] = pk2(a1.x, a1.y); cah.u[3] = pk2(a1.z, a1.w);
            cal.u[0] = pk2(a0.x - lo_f(cah.u[0]), a0.y - hi_f(cah.u[0]));
            cal.u[1] = pk2(a0.z - lo_f(cah.u[1]), a0.w - hi_f(cah.u[1]));
            cal.u[2] = pk2(a1.x - lo_f(cah.u[2]), a1.y - hi_f(cah.u[2]));
            cal.u[3] = pk2(a1.z - lo_f(cah.u[3]), a1.w - hi_f(cah.u[3]));
            acc[f] = __builtin_amdgcn_mfma_f32_16x16x32_bf16(cah.s, bh, acc[f], 0, 0, 0);
            acc[f] = __builtin_amdgcn_mfma_f32_16x16x32_bf16(cal.s, bh, acc[f], 0, 0, 0);
            acc[f] = __builtin_amdgcn_mfma_f32_16x16x32_bf16(cah.s, bl, acc[f], 0, 0, 0);
        }
    }
#pragma unroll
    for (int f = 0; f < 10; ++f)
#pragma unroll
        for (int j = 0; j < 4; ++j) red[w][f][g * 4 + j][l15] = acc[f][j];
    __syncthreads();
    if (tid < 160) {
        const int f = tid >> 4, m = tid & 15;
        float s = 0.f;
#pragma unroll
        for (int n = 0; n < 16; ++n) {
            float v = red[0][f][m][n] + red[1][f][m][n] + red[2][f][m][n] + red[3][f][m][n];
            zp[(size_t)tid * F_ + n0 + n] = v;
            s = fmaf(v, v, s);
        }
        atomicAdd(&sqp[tid], s);
    }
}

__global__ __launch_bounds__(128)
void k_u(const float* __restrict__ zp, const float* __restrict__ om,
         float* __restrict__ u) {
    const int c  = blockIdx.x * 128 + threadIdx.x;
    const int r0 = blockIdx.y * 32;
    const int kz = blockIdx.z * 128;
    __shared__ __align__(16) float zt[128][36];
    for (int i = threadIdx.x; i < 128 * 32; i += 128) {
        int k = i >> 5, r = i & 31;
        zt[k][r] = zp[(size_t)(r0 + r) * F_ + kz + k];
    }
    __syncthreads();
    float acc[32];
#pragma unroll
    for (int r = 0; r < 32; ++r) acc[r] = 0.f;
    for (int k = 0; k < 128; ++k) {
        float o = om[(size_t)(kz + k) * F_ + c];
        const float4* zr = reinterpret_cast<const float4*>(&zt[k][0]);
#pragma unroll
        for (int r4 = 0; r4 < 8; ++r4) {
            float4 z4 = zr[r4];
            acc[r4 * 4 + 0] = fmaf(z4.x, o, acc[r4 * 4 + 0]);
            acc[r4 * 4 + 1] = fmaf(z4.y, o, acc[r4 * 4 + 1]);
            acc[r4 * 4 + 2] = fmaf(z4.z, o, acc[r4 * 4 + 2]);
            acc[r4 * 4 + 3] = fmaf(z4.w, o, acc[r4 * 4 + 3]);
        }
    }
#pragma unroll
    for (int r = 0; r < 32; ++r) atomicAdd(&u[(size_t)(r0 + r) * F_ + c], acc[r]);
}

__global__ __launch_bounds__(256)
void k_usplit(const float* __restrict__ u, ushort_t* __restrict__ uh) {
    const int b = blockIdx.x, t = threadIdx.x;
    float4 v = *reinterpret_cast<const float4*>(u + (size_t)b * F_ + t * 4);
    unsigned h0 = pk2(v.x, v.y), h1 = pk2(v.z, v.w);
    *reinterpret_cast<uint2*>(uh + (size_t)b * F_ + t * 4) = make_uint2(h0, h1);
}

// ---- launch --------------------------------------------------------------

extern "C" void kernel_launch(void* const* d_in, const int* in_sizes, int n_in,
                              void* d_out, int out_size, void* d_ws, size_t ws_size,
                              hipStream_t stream) {
    (void)in_sizes; (void)n_in; (void)out_size;
    const float* x    = (const float*)d_in[0];
    const float* prot = (const float*)d_in[1];
    const float* om   = (const float*)d_in[2];

    float* out  = (float*)d_out;
    float* dist = out;
    float* pred = out + (size_t)B_ * P_;

    char* W = (char*)d_ws;
    float* sqx = (float*)W;                    // 32768 B
    float* sqp = (float*)(W + 32768);          // 1024 B
    size_t o = 33792;
    ushort_t* phl   = (ushort_t*)(W + o); o += 327680;
    ushort_t* pll   = (ushort_t*)(W + o); o += 327680;
    ushort_t* zph   = (ushort_t*)(W + o); o += 327680;
    ushort_t* zpl   = (ushort_t*)(W + o); o += 327680;
    ushort_t* uh    = (ushort_t*)(W + o); o += 327680;
    ushort_t* up    = (ushort_t*)(W + o); o += 327680;    // packed u
    ushort_t* omh_r = (ushort_t*)(W + o); o += 2097152;
    ushort_t* oml_r = (ushort_t*)(W + o); o += 2097152;
    ushort_t* omTh  = (ushort_t*)(W + o); o += 2097152;
    ushort_t* omTl  = (ushort_t*)(W + o); o += 2097152;
    ushort_t* omh_sw= (ushort_t*)(W + o); o += 2097152;   // ~12.49 MB so far
    ushort_t* xh    = (ushort_t*)(W + o);                 // +16 MB -> ~29.3 MB

    const int tier = (ws_size >= (size_t)30 * 1024 * 1024) ? 2
                   : (ws_size >= (size_t)13 * 1024 * 1024) ? 1 : 0;

    if (tier == 2) {
        // 3 launches: prep(+x-cvt+zero+zp) -> {u+sqp | sq_x GEMM} -> dist
        k_prep1<<<267 + 4096 + 160, 256, 0, stream>>>(om, prot, x, omh_r, oml_r,
                                                      omTh, omTl, omh_sw, phl, pll,
                                                      xh, (float4*)W, zph, zpl, 2);
        k_u2z  <<<160 + 512, 256, 0, stream>>>(zph, zpl, omTh, omTl, uh, up,
                                               xh, omh_sw, sqx, sqp);
        k_dist5<<<512, 512, 0, stream>>>(xh, up, sqx, sqp, dist, pred);
    } else if (tier == 1) {
        k_prep1<<<267, 256, 0, stream>>>(om, prot, x, omh_r, oml_r, omTh,
                                         omTl, omh_sw, phl, pll, xh, (float4*)W,
                                         zph, zpl, 1);
        k_zp2  <<<160, 256, 0, stream>>>(phl, pll, omh_r, oml_r, zph, zpl, sqp);
        k_u2z  <<<160, 256, 0, stream>>>(zph, zpl, omTh, omTl, uh, up,
                                         xh, omh_sw, sqx, sqp);
        k_z_sqx<<<dim3(64, 8), 256, 0, stream>>>(x, om, sqx);
        k_dist2<<<512, 256, 0, stream>>>(x, uh, sqx, sqp, dist, pred);
    } else {
        float* wsf = (float*)d_ws;
        float* zp  = wsf + 8448;
        float* u   = wsf + 172288;
        ushort_t* uh0 = (ushort_t*)(wsf + 8448);
        hipMemsetAsync(wsf, 0, 33792, stream);
        hipMemsetAsync(u, 0, (size_t)P_ * F_ * sizeof(float), stream);
        k_proj  <<<64, 256, 0, stream>>>(prot, om, zp, sqp);
        k_u     <<<dim3(8, 5, 8), 128, 0, stream>>>(zp, om, u);
        k_usplit<<<160, 256, 0, stream>>>(u, uh0);
        k_z_sqx <<<dim3(64, 8), 256, 0, stream>>>(x, om, sqx);
        k_dist2 <<<512, 256, 0, stream>>>(x, uh0, sqx, sqp, dist, pred);
    }
}

// Round 11
// 82.318 us; speedup vs baseline: 1.1428x; 1.1428x over previous
//
#include <hip/hip_runtime.h>
#include <hip/hip_bf16.h>

#define B_ 8192
#define F_ 1024
#define P_ 160
#define C_ 10

typedef __attribute__((ext_vector_type(8))) short short8;
typedef __attribute__((ext_vector_type(4))) float f32x4;
typedef unsigned short ushort_t;

// ---- helpers -------------------------------------------------------------

__device__ inline unsigned pk2(float a, float b) {
    __hip_bfloat162 h = __float22bfloat162_rn(make_float2(a, b));
    return *reinterpret_cast<unsigned*>(&h);
}
__device__ inline float lo_f(unsigned u) { return __uint_as_float(u << 16); }
__device__ inline float hi_f(unsigned u) { return __uint_as_float(u & 0xffff0000u); }

__device__ inline void gload16(const void* g, void* l) {
    __builtin_amdgcn_global_load_lds((const __attribute__((address_space(1))) unsigned*)g,
                                     (__attribute__((address_space(3))) unsigned*)l, 16, 0, 0);
}

// ---- k_prep1: om/prot conversions + zero (267 blocks) --------------------
__global__ __launch_bounds__(256)
void k_prep1(const float* __restrict__ om, const float* __restrict__ prot,
             ushort_t* __restrict__ omh_r, ushort_t* __restrict__ oml_r,
             ushort_t* __restrict__ omTh, ushort_t* __restrict__ omTl,
             ushort_t* __restrict__ omh_sw,
             ushort_t* __restrict__ phl, ushort_t* __restrict__ pll,
             float4* __restrict__ zero_dst) {
    const int bid = blockIdx.x, tid = threadIdx.x;
    if (bid < 256) {
        const int tr = bid >> 4, tc = bid & 15;
        __shared__ float tile[64][65];
        const int r0 = tid >> 4, cq = (tid & 15) * 4;
#pragma unroll
        for (int i = 0; i < 4; ++i) {
            const int row = r0 + i * 16;
            const int gr = tr * 64 + row;
            float4 v = *reinterpret_cast<const float4*>(om + (size_t)gr * F_ + tc * 64 + cq);
            tile[row][cq + 0] = v.x; tile[row][cq + 1] = v.y;
            tile[row][cq + 2] = v.z; tile[row][cq + 3] = v.w;
            unsigned h0 = pk2(v.x, v.y), h1 = pk2(v.z, v.w);
            unsigned l0 = pk2(v.x - lo_f(h0), v.y - hi_f(h0));
            unsigned l1 = pk2(v.z - lo_f(h1), v.w - hi_f(h1));
            size_t ro = (size_t)gr * F_ + tc * 64 + cq;
            *reinterpret_cast<uint2*>(omh_r + ro) = make_uint2(h0, h1);
            *reinterpret_cast<uint2*>(oml_r + ro) = make_uint2(l0, l1);
            const int rb = gr >> 7, r = gr & 127;
            const int c0 = tc * 64 + cq;
            const int t32 = c0 >> 5, k8 = (c0 >> 3) & 3, half = (c0 >> 2) & 1;
            size_t base = ((size_t)(rb * 32 + t32)) * 8192;
            int off = (r * 64 + k8 * 16) ^ ((r & 7) << 4);
            *reinterpret_cast<uint2*>(reinterpret_cast<char*>(omh_sw) + base + off + half * 8) =
                make_uint2(h0, h1);
        }
        __syncthreads();
#pragma unroll
        for (int i = 0; i < 4; ++i) {
            const int rowT = r0 + i * 16;
            float a = tile[cq + 0][rowT], b = tile[cq + 1][rowT];
            float c = tile[cq + 2][rowT], d = tile[cq + 3][rowT];
            unsigned h0 = pk2(a, b), h1 = pk2(c, d);
            unsigned l0 = pk2(a - lo_f(h0), b - hi_f(h0));
            unsigned l1 = pk2(c - lo_f(h1), d - hi_f(h1));
            size_t to = (size_t)(tc * 64 + rowT) * F_ + tr * 64 + cq;
            *reinterpret_cast<uint2*>(omTh + to) = make_uint2(h0, h1);
            *reinterpret_cast<uint2*>(omTl + to) = make_uint2(l0, l1);
        }
    } else if (bid < 266) {
        const int pb = bid - 256;
        const int row = pb * 16 + (tid >> 4);
#pragma unroll
        for (int i = 0; i < 16; ++i) {
            const int col = (tid & 15) * 4 + i * 64;
            float4 v = *reinterpret_cast<const float4*>(prot + (size_t)row * F_ + col);
            unsigned h0 = pk2(v.x, v.y), h1 = pk2(v.z, v.w);
            unsigned l0 = pk2(v.x - lo_f(h0), v.y - hi_f(h0));
            unsigned l1 = pk2(v.z - lo_f(h1), v.w - hi_f(h1));
            size_t ro = (size_t)row * F_ + col;
            *reinterpret_cast<uint2*>(phl + ro) = make_uint2(h0, h1);
            *reinterpret_cast<uint2*>(pll + ro) = make_uint2(l0, l1);
        }
    } else {
        const float4 z = make_float4(0.f, 0.f, 0.f, 0.f);
        for (int i = tid; i < 2112; i += 256) zero_dst[i] = z;
    }
}

// ---- k_zp2x: {zp GEMM + sqp} (blocks 0..159) || {x -> xh cvt} (160+) -----
__global__ __launch_bounds__(256)
void k_zp2x(const ushort_t* __restrict__ phl, const ushort_t* __restrict__ pll,
            const ushort_t* __restrict__ omh_r, const ushort_t* __restrict__ oml_r,
            ushort_t* __restrict__ zph, ushort_t* __restrict__ zpl,
            float* __restrict__ sqp,
            const float* __restrict__ x, ushort_t* __restrict__ xh) {
    const int tid = threadIdx.x;
    if (blockIdx.x < 160) {
        const int lane = tid & 63, w = tid >> 6;
        const int fid = blockIdx.x * 4 + w;
        const int m = fid >> 6, n = fid & 63;
        const int l15 = lane & 15, g = lane >> 4;

        f32x4 acc = {};
        const ushort_t* pa_h = phl + (size_t)(m * 16 + l15) * F_ + g * 8;
        const ushort_t* pa_l = pll + (size_t)(m * 16 + l15) * F_ + g * 8;
        const ushort_t* pb_h = omh_r + (size_t)(n * 16 + l15) * F_ + g * 8;
        const ushort_t* pb_l = oml_r + (size_t)(n * 16 + l15) * F_ + g * 8;
#pragma unroll 4
        for (int ks = 0; ks < 32; ++ks) {
            short8 ah = *reinterpret_cast<const short8*>(pa_h + ks * 32);
            short8 al = *reinterpret_cast<const short8*>(pa_l + ks * 32);
            short8 bh = *reinterpret_cast<const short8*>(pb_h + ks * 32);
            short8 bl = *reinterpret_cast<const short8*>(pb_l + ks * 32);
            acc = __builtin_amdgcn_mfma_f32_16x16x32_bf16(ah, bh, acc, 0, 0, 0);
            acc = __builtin_amdgcn_mfma_f32_16x16x32_bf16(al, bh, acc, 0, 0, 0);
            acc = __builtin_amdgcn_mfma_f32_16x16x32_bf16(ah, bl, acc, 0, 0, 0);
        }
#pragma unroll
        for (int j = 0; j < 4; ++j) {
            float v = acc[j];
            const int row = m * 16 + g * 4 + j, col = n * 16 + l15;
            unsigned hv = pk2(v, 0.f);
            unsigned lv = pk2(v - lo_f(hv), 0.f);
            zph[(size_t)row * F_ + col] = (ushort_t)hv;
            zpl[(size_t)row * F_ + col] = (ushort_t)lv;
            float s = v * v;
            s += __shfl_xor(s, 1); s += __shfl_xor(s, 2);
            s += __shfl_xor(s, 4); s += __shfl_xor(s, 8);
            if (l15 == 0) atomicAdd(&sqp[row], s);
        }
    } else {
        // x -> pre-swizzled bf16 tiles (one 16B chunk per thread)
        const int c = (blockIdx.x - 160) * 256 + tid;
        const int rg = c >> 7, kg = c & 127;
        const int t = kg >> 2, k8 = kg & 3;
        const float4* s4 = reinterpret_cast<const float4*>(x + (size_t)rg * F_ + t * 32 + k8 * 8);
        float4 v0 = s4[0], v1 = s4[1];
        uint4 o;
        o.x = pk2(v0.x, v0.y); o.y = pk2(v0.z, v0.w);
        o.z = pk2(v1.x, v1.y); o.w = pk2(v1.z, v1.w);
        const int rb = rg >> 7, r = rg & 127;
        size_t base = ((size_t)(rb * 32 + t)) * 8192;
        int off = (r * 64 + k8 * 16) ^ ((r & 7) << 4);
        *reinterpret_cast<uint4*>(reinterpret_cast<char*>(xh) + base + off) = o;
    }
}

// ---- k_u2z: fused {u = zp @ om} + {sq_x GEMM} (R7 verbatim) --------------
__global__ __launch_bounds__(256)
void k_u2z(const ushort_t* __restrict__ zph, const ushort_t* __restrict__ zpl,
           const ushort_t* __restrict__ omTh, const ushort_t* __restrict__ omTl,
           ushort_t* __restrict__ uh, ushort_t* __restrict__ up,
           const ushort_t* __restrict__ xh, const ushort_t* __restrict__ omh_sw,
           float* __restrict__ sqx) {
    __shared__ __align__(16) ushort_t sA[128 * 32];
    __shared__ __align__(16) ushort_t sB[128 * 32];
    const int tid = threadIdx.x;
    const int lane = tid & 63, w = tid >> 6;
    const int l15 = lane & 15, g = lane >> 4;

    if (blockIdx.x < 160) {
        const int fid = blockIdx.x * 4 + w;
        const int m = fid >> 6, n = fid & 63;
        f32x4 acc = {};
        const ushort_t* pa_h = zph + (size_t)(m * 16 + l15) * F_ + g * 8;
        const ushort_t* pa_l = zpl + (size_t)(m * 16 + l15) * F_ + g * 8;
        const ushort_t* pb_h = omTh + (size_t)(n * 16 + l15) * F_ + g * 8;
        const ushort_t* pb_l = omTl + (size_t)(n * 16 + l15) * F_ + g * 8;
#pragma unroll 4
        for (int ks = 0; ks < 32; ++ks) {
            short8 ah = *reinterpret_cast<const short8*>(pa_h + ks * 32);
            short8 al = *reinterpret_cast<const short8*>(pa_l + ks * 32);
            short8 bh = *reinterpret_cast<const short8*>(pb_h + ks * 32);
            short8 bl = *reinterpret_cast<const short8*>(pb_l + ks * 32);
            acc = __builtin_amdgcn_mfma_f32_16x16x32_bf16(ah, bh, acc, 0, 0, 0);
            acc = __builtin_amdgcn_mfma_f32_16x16x32_bf16(al, bh, acc, 0, 0, 0);
            acc = __builtin_amdgcn_mfma_f32_16x16x32_bf16(ah, bl, acc, 0, 0, 0);
        }
#pragma unroll
        for (int j = 0; j < 4; ++j) {
            float v = acc[j];
            const int rr = g * 4 + j;
            const int row = m * 16 + rr, col = n * 16 + l15;
            unsigned hv = pk2(v, 0.f);
            ushort_t hs = (ushort_t)hv;
            uh[(size_t)row * F_ + col] = hs;
            const int ks = col >> 5, gg = (col >> 3) & 3, e = col & 7;
            up[(((size_t)m * 32 + ks) * 64 + gg * 16 + rr) * 8 + e] = hs;
        }
    } else {
        const int zb = blockIdx.x - 160;
        const int bx = zb & 63, by = zb >> 6;
        const int wr = (w >> 1) * 64, wc = (w & 1) * 64;
        f32x4 acc[4][4] = {};
        const char* xb = reinterpret_cast<const char*>(xh) + (size_t)bx * 32 * 8192;
        const char* ob = reinterpret_cast<const char*>(omh_sw) + (size_t)by * 32 * 8192;
        char* sAc = reinterpret_cast<char*>(sA);
        char* sBc = reinterpret_cast<char*>(sB);
        for (int t = 0; t < 32; ++t) {
            __syncthreads();
            gload16(xb + (size_t)t * 8192 + tid * 16,        sAc + tid * 16);
            gload16(xb + (size_t)t * 8192 + 4096 + tid * 16, sAc + 4096 + tid * 16);
            gload16(ob + (size_t)t * 8192 + tid * 16,        sBc + tid * 16);
            gload16(ob + (size_t)t * 8192 + 4096 + tid * 16, sBc + 4096 + tid * 16);
            __syncthreads();
            short8 a[4], b[4];
#pragma unroll
            for (int m = 0; m < 4; ++m) {
                int row = wr + m * 16 + l15;
                int off = (row * 64 + g * 16) ^ ((row & 7) << 4);
                a[m] = *reinterpret_cast<const short8*>(sAc + off);
            }
#pragma unroll
            for (int n = 0; n < 4; ++n) {
                int row = wc + n * 16 + l15;
                int off = (row * 64 + g * 16) ^ ((row & 7) << 4);
                b[n] = *reinterpret_cast<const short8*>(sBc + off);
            }
#pragma unroll
            for (int m = 0; m < 4; ++m)
#pragma unroll
                for (int n = 0; n < 4; ++n)
                    acc[m][n] = __builtin_amdgcn_mfma_f32_16x16x32_bf16(a[m], b[n], acc[m][n], 0, 0, 0);
        }
#pragma unroll
        for (int m = 0; m < 4; ++m) {
#pragma unroll
            for (int j = 0; j < 4; ++j) {
                float s = 0.f;
#pragma unroll
                for (int n = 0; n < 4; ++n) { float v = acc[m][n][j]; s = fmaf(v, v, s); }
                s += __shfl_xor(s, 1); s += __shfl_xor(s, 2);
                s += __shfl_xor(s, 4); s += __shfl_xor(s, 8);
                if (l15 == 0) atomicAdd(&sqx[bx * 128 + wr + m * 16 + g * 4 + j], s);
            }
        }
    }
}

// ---- k_dist5 (R7 verbatim): M-tile 16, 8 waves (K-quarter x N-half) ------
__global__ __launch_bounds__(512)
void k_dist5(const ushort_t* __restrict__ xh, const ushort_t* __restrict__ up,
             const float* __restrict__ sqx, const float* __restrict__ sqp,
             float* __restrict__ dist, float* __restrict__ pred) {
    const int brow = blockIdx.x * 16;
    const int tid = threadIdx.x, lane = tid & 63, w = tid >> 6;
    const int wk = w & 3, nh = w >> 2;
    const int l15 = lane & 15, g = lane >> 4;
    __shared__ float red[4][10][16][16];
    __shared__ float cminv[16][2];
    __shared__ int   cmini[16][2];

    f32x4 acc[5] = {};
    const int rb = brow >> 7, r = (brow & 127) + l15;
    const char* xb = reinterpret_cast<const char*>(xh) +
                     ((size_t)(rb * 32 + wk * 8)) * 8192 +
                     (((r * 64 + g * 16)) ^ ((r & 7) << 4));

#pragma unroll
    for (int ksl = 0; ksl < 8; ++ksl) {
        short8 ah = *reinterpret_cast<const short8*>(xb + (size_t)ksl * 8192);
#pragma unroll
        for (int f = 0; f < 5; ++f) {
            const int fg = nh * 5 + f;
            short8 bh = *reinterpret_cast<const short8*>(
                up + (((size_t)fg * 32 + wk * 8 + ksl) * 64 + lane) * 8);
            acc[f] = __builtin_amdgcn_mfma_f32_16x16x32_bf16(ah, bh, acc[f], 0, 0, 0);
        }
    }

#pragma unroll
    for (int f = 0; f < 5; ++f)
#pragma unroll
        for (int j = 0; j < 4; ++j)
            red[wk][nh * 5 + f][g * 4 + j][l15 ^ g] = acc[f][j];
    __syncthreads();

    const int fh = tid >> 8, m = (tid >> 4) & 15, n = tid & 15;
    const int row = brow + m;
    const int nn = n ^ (m >> 2);
    const float sx = sqx[row];
    float best = 3.4e38f; int bi = 0;
#pragma unroll
    for (int f = 0; f < 5; ++f) {
        const int fg = fh * 5 + f;
        float d = red[0][fg][m][nn] + red[1][fg][m][nn] +
                  red[2][fg][m][nn] + red[3][fg][m][nn];
        float dv = sx + sqp[fg * 16 + n] - 2.f * d;
        dist[(size_t)row * P_ + fg * 16 + n] = dv;
        float mn = dv;
        mn = fminf(mn, __shfl_xor(mn, 1));
        mn = fminf(mn, __shfl_xor(mn, 2));
        mn = fminf(mn, __shfl_xor(mn, 4));
        mn = fminf(mn, __shfl_xor(mn, 8));
        if (mn < best) { best = mn; bi = fg; }   // strict '<' => first min
    }
    if (n == 0) { cminv[m][fh] = best; cmini[m][fh] = bi; }
    __syncthreads();
    if (tid < 16) {
        float v0 = cminv[tid][0], v1 = cminv[tid][1];
        pred[brow + tid] = (float)((v1 < v0) ? cmini[tid][1] : cmini[tid][0]);
    }
}

// ---- tier-1 fallbacks ----------------------------------------------------

__global__ __launch_bounds__(256)
void k_z_sqx(const float* __restrict__ x, const float* __restrict__ om,
             float* __restrict__ sqx) {
    const int brow = blockIdx.x * 128;
    const int bcol = blockIdx.y * 128;
    __shared__ __align__(16) ushort_t sA[128 * 32];
    __shared__ __align__(16) ushort_t sB[128 * 32];
    const int tid = threadIdx.x;
    const int lane = tid & 63, w = tid >> 6;
    const int wr = (w >> 1) * 64, wc = (w & 1) * 64;
    const int l15 = lane & 15, g = lane >> 4;
    f32x4 acc[4][4] = {};
    for (int k0 = 0; k0 < F_; k0 += 32) {
        __syncthreads();
#pragma unroll
        for (int j = 0; j < 4; ++j) {
            int idx = tid + j * 256;
            int row = idx >> 3, c4 = idx & 7;
            float4 va = *reinterpret_cast<const float4*>(x  + (size_t)(brow + row) * F_ + k0 + c4 * 4);
            float4 vb = *reinterpret_cast<const float4*>(om + (size_t)(bcol + row) * F_ + k0 + c4 * 4);
            int off = (row * 64 + c4 * 8) ^ ((row & 7) << 4);
            *reinterpret_cast<uint2*>(reinterpret_cast<char*>(sA) + off) =
                make_uint2(pk2(va.x, va.y), pk2(va.z, va.w));
            *reinterpret_cast<uint2*>(reinterpret_cast<char*>(sB) + off) =
                make_uint2(pk2(vb.x, vb.y), pk2(vb.z, vb.w));
        }
        __syncthreads();
        short8 a[4], b[4];
#pragma unroll
        for (int m = 0; m < 4; ++m) {
            int row = wr + m * 16 + l15;
            int off = (row * 64 + g * 16) ^ ((row & 7) << 4);
            a[m] = *reinterpret_cast<const short8*>(reinterpret_cast<const char*>(sA) + off);
        }
#pragma unroll
        for (int n = 0; n < 4; ++n) {
            int row = wc + n * 16 + l15;
            int off = (row * 64 + g * 16) ^ ((row & 7) << 4);
            b[n] = *reinterpret_cast<const short8*>(reinterpret_cast<const char*>(sB) + off);
        }
#pragma unroll
        for (int m = 0; m < 4; ++m)
#pragma unroll
            for (int n = 0; n < 4; ++n)
                acc[m][n] = __builtin_amdgcn_mfma_f32_16x16x32_bf16(a[m], b[n], acc[m][n], 0, 0, 0);
    }
#pragma unroll
    for (int m = 0; m < 4; ++m) {
#pragma unroll
        for (int j = 0; j < 4; ++j) {
            float s = 0.f;
#pragma unroll
            for (int n = 0; n < 4; ++n) { float v = acc[m][n][j]; s = fmaf(v, v, s); }
            s += __shfl_xor(s, 1); s += __shfl_xor(s, 2);
            s += __shfl_xor(s, 4); s += __shfl_xor(s, 8);
            if (l15 == 0) atomicAdd(&sqx[brow + wr + m * 16 + g * 4 + j], s);
        }
    }
}

__global__ __launch_bounds__(256)
void k_dist2(const float* __restrict__ x, const ushort_t* __restrict__ uh,
             const float* __restrict__ sqx, const float* __restrict__ sqp,
             float* __restrict__ dist, float* __restrict__ pred) {
    const int brow = blockIdx.x * 16;
    const int tid = threadIdx.x, lane = tid & 63, w = tid >> 6;
    const int l15 = lane & 15, g = lane >> 4;
    __shared__ float red[4][10][16][16];

    f32x4 acc[10] = {};
    const float* xp = x + (size_t)(brow + l15) * F_ + w * 256 + g * 8;
    const ushort_t* buh = uh + (size_t)l15 * F_ + w * 256 + g * 8;

#pragma unroll 2
    for (int ks = 0; ks < 8; ++ks) {
        float4 v0 = *reinterpret_cast<const float4*>(xp + ks * 32);
        float4 v1 = *reinterpret_cast<const float4*>(xp + ks * 32 + 4);
        union { unsigned u[4]; short8 s; } cva;
        cva.u[0] = pk2(v0.x, v0.y); cva.u[1] = pk2(v0.z, v0.w);
        cva.u[2] = pk2(v1.x, v1.y); cva.u[3] = pk2(v1.z, v1.w);
        short8 ah = cva.s;
#pragma unroll
        for (int f = 0; f < 10; ++f) {
            short8 bh = *reinterpret_cast<const short8*>(buh + (size_t)f * 16 * F_ + ks * 32);
            acc[f] = __builtin_amdgcn_mfma_f32_16x16x32_bf16(ah, bh, acc[f], 0, 0, 0);
        }
    }
#pragma unroll
    for (int f = 0; f < 10; ++f)
#pragma unroll
        for (int j = 0; j < 4; ++j) red[w][f][g * 4 + j][l15 ^ g] = acc[f][j];
    __syncthreads();
    const int m = tid >> 4, n = tid & 15;
    const int row = brow + m;
    const int nn = n ^ (m >> 2);
    float sx = sqx[row];
    float best = 3.4e38f; int bi = 0;
#pragma unroll
    for (int f = 0; f < 10; ++f) {
        float d = red[0][f][m][nn] + red[1][f][m][nn] + red[2][f][m][nn] + red[3][f][m][nn];
        float dv = sx + sqp[f * 16 + n] - 2.f * d;
        dist[(size_t)row * P_ + f * 16 + n] = dv;
        float mn = dv;
        mn = fminf(mn, __shfl_xor(mn, 1));
        mn = fminf(mn, __shfl_xor(mn, 2));
        mn = fminf(mn, __shfl_xor(mn, 4));
        mn = fminf(mn, __shfl_xor(mn, 8));
        if (mn < best) { best = mn; bi = f; }
    }
    if (n == 0) pred[row] = (float)bi;
}

// ---- tier-0 fallback kernels (R3 path) -----------------------------------

__global__ __launch_bounds__(256)
void k_proj(const float* __restrict__ prot, const float* __restrict__ om,
            float* __restrict__ zp, float* __restrict__ sqp) {
    const int n0 = blockIdx.x * 16;
    const int tid = threadIdx.x, lane = tid & 63, w = tid >> 6;
    const int l15 = lane & 15, g = lane >> 4;
    __shared__ float red[4][10][16][16];
    f32x4 acc[10] = {};
    const float* op = om   + (size_t)(n0 + l15) * F_ + w * 256 + g * 8;
    const float* pp = prot + (size_t)l15 * F_ + w * 256 + g * 8;
#pragma unroll 2
    for (int ks = 0; ks < 8; ++ks) {
        float4 b0 = *reinterpret_cast<const float4*>(op + ks * 32);
        float4 b1 = *reinterpret_cast<const float4*>(op + ks * 32 + 4);
        union { unsigned u[4]; short8 s; } cbh, cbl;
        cbh.u[0] = pk2(b0.x, b0.y); cbh.u[1] = pk2(b0.z, b0.w);
        cbh.u[2] = pk2(b1.x, b1.y); cbh.u[3] = pk2(b1.z, b1.w);
        cbl.u[0] = pk2(b0.x - lo_f(cbh.u[0]), b0.y - hi_f(cbh.u[0]));
        cbl.u[1] = pk2(b0.z - lo_f(cbh.u[1]), b0.w - hi_f(cbh.u[1]));
        cbl.u[2] = pk2(b1.x - lo_f(cbh.u[2]), b1.y - hi_f(cbh.u[2]));
        cbl.u[3] = pk2(b1.z - lo_f(cbh.u[3]), b1.w - hi_f(cbh.u[3]));
        short8 bh = cbh.s, bl = cbl.s;
#pragma unroll
        for (int f = 0; f < 10; ++f) {
            float4 a0 = *reinterpret_cast<const float4*>(pp + (size_t)f * 16 * F_ + ks * 32);
            float4 a1 = *reinterpret_cast<const float4*>(pp + (size_t)f * 16 * F_ + ks * 32 + 4);
            union { unsigned u[4]; short8 s; } cah, cal;
            cah.u[0] = pk2(a0.x, a0.y); cah.u[1] = pk2(a0.z, a0.w);
            cah.u[2] = pk2(a1.x, a1.y); cah.u[3] = pk2(a1.z, a1.w);
            cal.u[0] = pk2(a0.x - lo_f(cah.u[0]), a0.y - hi_f(cah.u[0]));
            cal.u[1] = pk2(a0.z - lo_f(cah.u[1]), a0.w - hi_f(cah.u[1]));
            cal.u[2] = pk2(a1.x - lo_f(cah.u[2]), a1.y - hi_f(cah.u[2]));
            cal.u[3] = pk2(a1.z - lo_f(cah.u[3]), a1.w - hi_f(cah.u[3]));
            acc[f] = __builtin_amdgcn_mfma_f32_16x16x32_bf16(cah.s, bh, acc[f], 0, 0, 0);
            acc[f] = __builtin_amdgcn_mfma_f32_16x16x32_bf16(cal.s, bh, acc[f], 0, 0, 0);
            acc[f] = __builtin_amdgcn_mfma_f32_16x16x32_bf16(cah.s, bl, acc[f], 0, 0, 0);
        }
    }
#pragma unroll
    for (int f = 0; f < 10; ++f)
#pragma unroll
        for (int j = 0; j < 4; ++j) red[w][f][g * 4 + j][l15] = acc[f][j];
    __syncthreads();
    if (tid < 160) {
        const int f = tid >> 4, m = tid & 15;
        float s = 0.f;
#pragma unroll
        for (int n = 0; n < 16; ++n) {
            float v = red[0][f][m][n] + red[1][f][m][n] + red[2][f][m][n] + red[3][f][m][n];
            zp[(size_t)tid * F_ + n0 + n] = v;
            s = fmaf(v, v, s);
        }
        atomicAdd(&sqp[tid], s);
    }
}

__global__ __launch_bounds__(128)
void k_u(const float* __restrict__ zp, const float* __restrict__ om,
         float* __restrict__ u) {
    const int c  = blockIdx.x * 128 + threadIdx.x;
    const int r0 = blockIdx.y * 32;
    const int kz = blockIdx.z * 128;
    __shared__ __align__(16) float zt[128][36];
    for (int i = threadIdx.x; i < 128 * 32; i += 128) {
        int k = i >> 5, r = i & 31;
        zt[k][r] = zp[(size_t)(r0 + r) * F_ + kz + k];
    }
    __syncthreads();
    float acc[32];
#pragma unroll
    for (int r = 0; r < 32; ++r) acc[r] = 0.f;
    for (int k = 0; k < 128; ++k) {
        float o = om[(size_t)(kz + k) * F_ + c];
        const float4* zr = reinterpret_cast<const float4*>(&zt[k][0]);
#pragma unroll
        for (int r4 = 0; r4 < 8; ++r4) {
            float4 z4 = zr[r4];
            acc[r4 * 4 + 0] = fmaf(z4.x, o, acc[r4 * 4 + 0]);
            acc[r4 * 4 + 1] = fmaf(z4.y, o, acc[r4 * 4 + 1]);
            acc[r4 * 4 + 2] = fmaf(z4.z, o, acc[r4 * 4 + 2]);
            acc[r4 * 4 + 3] = fmaf(z4.w, o, acc[r4 * 4 + 3]);
        }
    }
#pragma unroll
    for (int r = 0; r < 32; ++r) atomicAdd(&u[(size_t)(r0 + r) * F_ + c], acc[r]);
}

__global__ __launch_bounds__(256)
void k_usplit(const float* __restrict__ u, ushort_t* __restrict__ uh) {
    const int b = blockIdx.x, t = threadIdx.x;
    float4 v = *reinterpret_cast<const float4*>(u + (size_t)b * F_ + t * 4);
    unsigned h0 = pk2(v.x, v.y), h1 = pk2(v.z, v.w);
    *reinterpret_cast<uint2*>(uh + (size_t)b * F_ + t * 4) = make_uint2(h0, h1);
}

// ---- launch --------------------------------------------------------------

extern "C" void kernel_launch(void* const* d_in, const int* in_sizes, int n_in,
                              void* d_out, int out_size, void* d_ws, size_t ws_size,
                              hipStream_t stream) {
    (void)in_sizes; (void)n_in; (void)out_size;
    const float* x    = (const float*)d_in[0];
    const float* prot = (const float*)d_in[1];
    const float* om   = (const float*)d_in[2];

    float* out  = (float*)d_out;
    float* dist = out;
    float* pred = out + (size_t)B_ * P_;

    char* W = (char*)d_ws;
    float* sqx = (float*)W;                    // 32768 B
    float* sqp = (float*)(W + 32768);          // 1024 B
    size_t o = 33792;
    ushort_t* phl   = (ushort_t*)(W + o); o += 327680;
    ushort_t* pll   = (ushort_t*)(W + o); o += 327680;
    ushort_t* zph   = (ushort_t*)(W + o); o += 327680;
    ushort_t* zpl   = (ushort_t*)(W + o); o += 327680;
    ushort_t* uh    = (ushort_t*)(W + o); o += 327680;
    ushort_t* up    = (ushort_t*)(W + o); o += 327680;    // packed u
    ushort_t* omh_r = (ushort_t*)(W + o); o += 2097152;
    ushort_t* oml_r = (ushort_t*)(W + o); o += 2097152;
    ushort_t* omTh  = (ushort_t*)(W + o); o += 2097152;
    ushort_t* omTl  = (ushort_t*)(W + o); o += 2097152;
    ushort_t* omh_sw= (ushort_t*)(W + o); o += 2097152;   // ~12.49 MB so far
    ushort_t* xh    = (ushort_t*)(W + o);                 // +16 MB -> ~29.3 MB

    const int tier = (ws_size >= (size_t)30 * 1024 * 1024) ? 2
                   : (ws_size >= (size_t)13 * 1024 * 1024) ? 1 : 0;

    if (tier == 2) {
        // 4 launches: prep(om/prot/zero) -> {zp | x-cvt} -> {u | sq_x} -> dist
        k_prep1<<<267, 256, 0, stream>>>(om, prot, omh_r, oml_r, omTh, omTl,
                                         omh_sw, phl, pll, (float4*)W);
        k_zp2x <<<160 + 4096, 256, 0, stream>>>(phl, pll, omh_r, oml_r,
                                                zph, zpl, sqp, x, xh);
        k_u2z  <<<160 + 512, 256, 0, stream>>>(zph, zpl, omTh, omTl, uh, up,
                                               xh, omh_sw, sqx);
        k_dist5<<<512, 512, 0, stream>>>(xh, up, sqx, sqp, dist, pred);
    } else if (tier == 1) {
        k_prep1<<<267, 256, 0, stream>>>(om, prot, omh_r, oml_r, omTh, omTl,
                                         omh_sw, phl, pll, (float4*)W);
        k_zp2x <<<160, 256, 0, stream>>>(phl, pll, omh_r, oml_r,
                                         zph, zpl, sqp, x, xh);
        k_u2z  <<<160, 256, 0, stream>>>(zph, zpl, omTh, omTl, uh, up,
                                         xh, omh_sw, sqx);
        k_z_sqx<<<dim3(64, 8), 256, 0, stream>>>(x, om, sqx);
        k_dist2<<<512, 256, 0, stream>>>(x, uh, sqx, sqp, dist, pred);
    } else {
        float* wsf = (float*)d_ws;
        float* zp  = wsf + 8448;
        float* u   = wsf + 172288;
        ushort_t* uh0 = (ushort_t*)(wsf + 8448);
        hipMemsetAsync(wsf, 0, 33792, stream);
        hipMemsetAsync(u, 0, (size_t)P_ * F_ * sizeof(float), stream);
        k_proj  <<<64, 256, 0, stream>>>(prot, om, zp, sqp);
        k_u     <<<dim3(8, 5, 8), 128, 0, stream>>>(zp, om, u);
        k_usplit<<<160, 256, 0, stream>>>(u, uh0);
        k_z_sqx <<<dim3(64, 8), 256, 0, stream>>>(x, om, sqx);
        k_dist2 <<<512, 256, 0, stream>>>(x, uh0, sqx, sqp, dist, pred);
    }
}

// Round 12
// 82.243 us; speedup vs baseline: 1.1438x; 1.0009x over previous
//
#include <hip/hip_runtime.h>
#include <hip/hip_bf16.h>

#define B_ 8192
#define F_ 1024
#define P_ 160
#define C_ 10

typedef __attribute__((ext_vector_type(8))) short short8;
typedef __attribute__((ext_vector_type(4))) float f32x4;
typedef unsigned short ushort_t;

// ---- helpers -------------------------------------------------------------

__device__ inline unsigned pk2(float a, float b) {
    __hip_bfloat162 h = __float22bfloat162_rn(make_float2(a, b));
    return *reinterpret_cast<unsigned*>(&h);
}
__device__ inline float lo_f(unsigned u) { return __uint_as_float(u << 16); }
__device__ inline float hi_f(unsigned u) { return __uint_as_float(u & 0xffff0000u); }

__device__ inline void gload16(const void* g, void* l) {
    __builtin_amdgcn_global_load_lds((const __attribute__((address_space(1))) unsigned*)g,
                                     (__attribute__((address_space(3))) unsigned*)l, 16, 0, 0);
}

// ---- k_prep1: om/prot conversions + zero (267 blocks) --------------------
__global__ __launch_bounds__(256)
void k_prep1(const float* __restrict__ om, const float* __restrict__ prot,
             ushort_t* __restrict__ omh_r, ushort_t* __restrict__ oml_r,
             ushort_t* __restrict__ omTh, ushort_t* __restrict__ omTl,
             ushort_t* __restrict__ omh_sw,
             ushort_t* __restrict__ phl, ushort_t* __restrict__ pll,
             float4* __restrict__ zero_dst) {
    const int bid = blockIdx.x, tid = threadIdx.x;
    if (bid < 256) {
        const int tr = bid >> 4, tc = bid & 15;
        __shared__ float tile[64][65];
        const int r0 = tid >> 4, cq = (tid & 15) * 4;
#pragma unroll
        for (int i = 0; i < 4; ++i) {
            const int row = r0 + i * 16;
            const int gr = tr * 64 + row;
            float4 v = *reinterpret_cast<const float4*>(om + (size_t)gr * F_ + tc * 64 + cq);
            tile[row][cq + 0] = v.x; tile[row][cq + 1] = v.y;
            tile[row][cq + 2] = v.z; tile[row][cq + 3] = v.w;
            unsigned h0 = pk2(v.x, v.y), h1 = pk2(v.z, v.w);
            unsigned l0 = pk2(v.x - lo_f(h0), v.y - hi_f(h0));
            unsigned l1 = pk2(v.z - lo_f(h1), v.w - hi_f(h1));
            size_t ro = (size_t)gr * F_ + tc * 64 + cq;
            *reinterpret_cast<uint2*>(omh_r + ro) = make_uint2(h0, h1);
            *reinterpret_cast<uint2*>(oml_r + ro) = make_uint2(l0, l1);
            const int rb = gr >> 7, r = gr & 127;
            const int c0 = tc * 64 + cq;
            const int t32 = c0 >> 5, k8 = (c0 >> 3) & 3, half = (c0 >> 2) & 1;
            size_t base = ((size_t)(rb * 32 + t32)) * 8192;
            int off = (r * 64 + k8 * 16) ^ ((r & 7) << 4);
            *reinterpret_cast<uint2*>(reinterpret_cast<char*>(omh_sw) + base + off + half * 8) =
                make_uint2(h0, h1);
        }
        __syncthreads();
#pragma unroll
        for (int i = 0; i < 4; ++i) {
            const int rowT = r0 + i * 16;
            float a = tile[cq + 0][rowT], b = tile[cq + 1][rowT];
            float c = tile[cq + 2][rowT], d = tile[cq + 3][rowT];
            unsigned h0 = pk2(a, b), h1 = pk2(c, d);
            unsigned l0 = pk2(a - lo_f(h0), b - hi_f(h0));
            unsigned l1 = pk2(c - lo_f(h1), d - hi_f(h1));
            size_t to = (size_t)(tc * 64 + rowT) * F_ + tr * 64 + cq;
            *reinterpret_cast<uint2*>(omTh + to) = make_uint2(h0, h1);
            *reinterpret_cast<uint2*>(omTl + to) = make_uint2(l0, l1);
        }
    } else if (bid < 266) {
        const int pb = bid - 256;
        const int row = pb * 16 + (tid >> 4);
#pragma unroll
        for (int i = 0; i < 16; ++i) {
            const int col = (tid & 15) * 4 + i * 64;
            float4 v = *reinterpret_cast<const float4*>(prot + (size_t)row * F_ + col);
            unsigned h0 = pk2(v.x, v.y), h1 = pk2(v.z, v.w);
            unsigned l0 = pk2(v.x - lo_f(h0), v.y - hi_f(h0));
            unsigned l1 = pk2(v.z - lo_f(h1), v.w - hi_f(h1));
            size_t ro = (size_t)row * F_ + col;
            *reinterpret_cast<uint2*>(phl + ro) = make_uint2(h0, h1);
            *reinterpret_cast<uint2*>(pll + ro) = make_uint2(l0, l1);
        }
    } else {
        const float4 z = make_float4(0.f, 0.f, 0.f, 0.f);
        for (int i = tid; i < 2112; i += 256) zero_dst[i] = z;
    }
}

// ---- k_zp2x: {zp GEMM + sqp} (blocks 0..159) || {x -> xh cvt} (160+) -----
__global__ __launch_bounds__(256)
void k_zp2x(const ushort_t* __restrict__ phl, const ushort_t* __restrict__ pll,
            const ushort_t* __restrict__ omh_r, const ushort_t* __restrict__ oml_r,
            ushort_t* __restrict__ zph, ushort_t* __restrict__ zpl,
            float* __restrict__ sqp,
            const float* __restrict__ x, ushort_t* __restrict__ xh) {
    const int tid = threadIdx.x;
    if (blockIdx.x < 160) {
        const int lane = tid & 63, w = tid >> 6;
        const int fid = blockIdx.x * 4 + w;
        const int m = fid >> 6, n = fid & 63;
        const int l15 = lane & 15, g = lane >> 4;

        f32x4 acc = {};
        const ushort_t* pa_h = phl + (size_t)(m * 16 + l15) * F_ + g * 8;
        const ushort_t* pa_l = pll + (size_t)(m * 16 + l15) * F_ + g * 8;
        const ushort_t* pb_h = omh_r + (size_t)(n * 16 + l15) * F_ + g * 8;
        const ushort_t* pb_l = oml_r + (size_t)(n * 16 + l15) * F_ + g * 8;
#pragma unroll 4
        for (int ks = 0; ks < 32; ++ks) {
            short8 ah = *reinterpret_cast<const short8*>(pa_h + ks * 32);
            short8 al = *reinterpret_cast<const short8*>(pa_l + ks * 32);
            short8 bh = *reinterpret_cast<const short8*>(pb_h + ks * 32);
            short8 bl = *reinterpret_cast<const short8*>(pb_l + ks * 32);
            acc = __builtin_amdgcn_mfma_f32_16x16x32_bf16(ah, bh, acc, 0, 0, 0);
            acc = __builtin_amdgcn_mfma_f32_16x16x32_bf16(al, bh, acc, 0, 0, 0);
            acc = __builtin_amdgcn_mfma_f32_16x16x32_bf16(ah, bl, acc, 0, 0, 0);
        }
#pragma unroll
        for (int j = 0; j < 4; ++j) {
            float v = acc[j];
            const int row = m * 16 + g * 4 + j, col = n * 16 + l15;
            unsigned hv = pk2(v, 0.f);
            unsigned lv = pk2(v - lo_f(hv), 0.f);
            zph[(size_t)row * F_ + col] = (ushort_t)hv;
            zpl[(size_t)row * F_ + col] = (ushort_t)lv;
            float s = v * v;
            s += __shfl_xor(s, 1); s += __shfl_xor(s, 2);
            s += __shfl_xor(s, 4); s += __shfl_xor(s, 8);
            if (l15 == 0) atomicAdd(&sqp[row], s);
        }
    } else {
        // x -> pre-swizzled bf16 tiles (one 16B chunk per thread)
        const int c = (blockIdx.x - 160) * 256 + tid;
        const int rg = c >> 7, kg = c & 127;
        const int t = kg >> 2, k8 = kg & 3;
        const float4* s4 = reinterpret_cast<const float4*>(x + (size_t)rg * F_ + t * 32 + k8 * 8);
        float4 v0 = s4[0], v1 = s4[1];
        uint4 o;
        o.x = pk2(v0.x, v0.y); o.y = pk2(v0.z, v0.w);
        o.z = pk2(v1.x, v1.y); o.w = pk2(v1.z, v1.w);
        const int rb = rg >> 7, r = rg & 127;
        size_t base = ((size_t)(rb * 32 + t)) * 8192;
        int off = (r * 64 + k8 * 16) ^ ((r & 7) << 4);
        *reinterpret_cast<uint4*>(reinterpret_cast<char*>(xh) + base + off) = o;
    }
}

// ---- k_u2z: fused {u = zp @ om} + {sq_x GEMM} ----------------------------
__global__ __launch_bounds__(256)
void k_u2z(const ushort_t* __restrict__ zph, const ushort_t* __restrict__ zpl,
           const ushort_t* __restrict__ omTh, const ushort_t* __restrict__ omTl,
           ushort_t* __restrict__ uh, ushort_t* __restrict__ up,
           const ushort_t* __restrict__ xh, const ushort_t* __restrict__ omh_sw,
           float* __restrict__ sqx) {
    __shared__ __align__(16) ushort_t sA[128 * 32];
    __shared__ __align__(16) ushort_t sB[128 * 32];
    const int tid = threadIdx.x;
    const int lane = tid & 63, w = tid >> 6;
    const int l15 = lane & 15, g = lane >> 4;

    if (blockIdx.x < 160) {
        const int fid = blockIdx.x * 4 + w;
        const int m = fid >> 6, n = fid & 63;
        f32x4 acc = {};
        const ushort_t* pa_h = zph + (size_t)(m * 16 + l15) * F_ + g * 8;
        const ushort_t* pa_l = zpl + (size_t)(m * 16 + l15) * F_ + g * 8;
        const ushort_t* pb_h = omTh + (size_t)(n * 16 + l15) * F_ + g * 8;
        const ushort_t* pb_l = omTl + (size_t)(n * 16 + l15) * F_ + g * 8;
#pragma unroll 4
        for (int ks = 0; ks < 32; ++ks) {
            short8 ah = *reinterpret_cast<const short8*>(pa_h + ks * 32);
            short8 al = *reinterpret_cast<const short8*>(pa_l + ks * 32);
            short8 bh = *reinterpret_cast<const short8*>(pb_h + ks * 32);
            short8 bl = *reinterpret_cast<const short8*>(pb_l + ks * 32);
            acc = __builtin_amdgcn_mfma_f32_16x16x32_bf16(ah, bh, acc, 0, 0, 0);
            acc = __builtin_amdgcn_mfma_f32_16x16x32_bf16(al, bh, acc, 0, 0, 0);
            acc = __builtin_amdgcn_mfma_f32_16x16x32_bf16(ah, bl, acc, 0, 0, 0);
        }
#pragma unroll
        for (int j = 0; j < 4; ++j) {
            float v = acc[j];
            const int rr = g * 4 + j;
            const int row = m * 16 + rr, col = n * 16 + l15;
            unsigned hv = pk2(v, 0.f);
            ushort_t hs = (ushort_t)hv;
            uh[(size_t)row * F_ + col] = hs;
            const int ks = col >> 5, gg = (col >> 3) & 3, e = col & 7;
            up[(((size_t)m * 32 + ks) * 64 + gg * 16 + rr) * 8 + e] = hs;
        }
    } else {
        const int zb = blockIdx.x - 160;
        const int bx = zb & 63, by = zb >> 6;
        const int wr = (w >> 1) * 64, wc = (w & 1) * 64;
        f32x4 acc[4][4] = {};
        const char* xb = reinterpret_cast<const char*>(xh) + (size_t)bx * 32 * 8192;
        const char* ob = reinterpret_cast<const char*>(omh_sw) + (size_t)by * 32 * 8192;
        char* sAc = reinterpret_cast<char*>(sA);
        char* sBc = reinterpret_cast<char*>(sB);
        for (int t = 0; t < 32; ++t) {
            __syncthreads();
            gload16(xb + (size_t)t * 8192 + tid * 16,        sAc + tid * 16);
            gload16(xb + (size_t)t * 8192 + 4096 + tid * 16, sAc + 4096 + tid * 16);
            gload16(ob + (size_t)t * 8192 + tid * 16,        sBc + tid * 16);
            gload16(ob + (size_t)t * 8192 + 4096 + tid * 16, sBc + 4096 + tid * 16);
            __syncthreads();
            short8 a[4], b[4];
#pragma unroll
            for (int m = 0; m < 4; ++m) {
                int row = wr + m * 16 + l15;
                int off = (row * 64 + g * 16) ^ ((row & 7) << 4);
                a[m] = *reinterpret_cast<const short8*>(sAc + off);
            }
#pragma unroll
            for (int n = 0; n < 4; ++n) {
                int row = wc + n * 16 + l15;
                int off = (row * 64 + g * 16) ^ ((row & 7) << 4);
                b[n] = *reinterpret_cast<const short8*>(sBc + off);
            }
#pragma unroll
            for (int m = 0; m < 4; ++m)
#pragma unroll
                for (int n = 0; n < 4; ++n)
                    acc[m][n] = __builtin_amdgcn_mfma_f32_16x16x32_bf16(a[m], b[n], acc[m][n], 0, 0, 0);
        }
#pragma unroll
        for (int m = 0; m < 4; ++m) {
#pragma unroll
            for (int j = 0; j < 4; ++j) {
                float s = 0.f;
#pragma unroll
                for (int n = 0; n < 4; ++n) { float v = acc[m][n][j]; s = fmaf(v, v, s); }
                s += __shfl_xor(s, 1); s += __shfl_xor(s, 2);
                s += __shfl_xor(s, 4); s += __shfl_xor(s, 8);
                if (l15 == 0) atomicAdd(&sqx[bx * 128 + wr + m * 16 + g * 4 + j], s);
            }
        }
    }
}

// ---- k_dist5: M-tile 16, 8 waves (K-quarter x N-half), + setprio (T5) ----
// Barrier-free K-loop => waves drift into different phases; setprio lets the
// CU scheduler favor MFMA-issuing waves (m191-regime, not m190's lockstep).
__global__ __launch_bounds__(512)
void k_dist5(const ushort_t* __restrict__ xh, const ushort_t* __restrict__ up,
             const float* __restrict__ sqx, const float* __restrict__ sqp,
             float* __restrict__ dist, float* __restrict__ pred) {
    const int brow = blockIdx.x * 16;
    const int tid = threadIdx.x, lane = tid & 63, w = tid >> 6;
    const int wk = w & 3, nh = w >> 2;
    const int l15 = lane & 15, g = lane >> 4;
    __shared__ float red[4][10][16][16];
    __shared__ float cminv[16][2];
    __shared__ int   cmini[16][2];

    f32x4 acc[5] = {};
    const int rb = brow >> 7, r = (brow & 127) + l15;
    const char* xb = reinterpret_cast<const char*>(xh) +
                     ((size_t)(rb * 32 + wk * 8)) * 8192 +
                     (((r * 64 + g * 16)) ^ ((r & 7) << 4));

#pragma unroll
    for (int ksl = 0; ksl < 8; ++ksl) {
        short8 ah = *reinterpret_cast<const short8*>(xb + (size_t)ksl * 8192);
        short8 bh0 = *reinterpret_cast<const short8*>(
            up + (((size_t)(nh * 5 + 0) * 32 + wk * 8 + ksl) * 64 + lane) * 8);
        short8 bh1 = *reinterpret_cast<const short8*>(
            up + (((size_t)(nh * 5 + 1) * 32 + wk * 8 + ksl) * 64 + lane) * 8);
        short8 bh2 = *reinterpret_cast<const short8*>(
            up + (((size_t)(nh * 5 + 2) * 32 + wk * 8 + ksl) * 64 + lane) * 8);
        short8 bh3 = *reinterpret_cast<const short8*>(
            up + (((size_t)(nh * 5 + 3) * 32 + wk * 8 + ksl) * 64 + lane) * 8);
        short8 bh4 = *reinterpret_cast<const short8*>(
            up + (((size_t)(nh * 5 + 4) * 32 + wk * 8 + ksl) * 64 + lane) * 8);
        __builtin_amdgcn_s_setprio(1);
        acc[0] = __builtin_amdgcn_mfma_f32_16x16x32_bf16(ah, bh0, acc[0], 0, 0, 0);
        acc[1] = __builtin_amdgcn_mfma_f32_16x16x32_bf16(ah, bh1, acc[1], 0, 0, 0);
        acc[2] = __builtin_amdgcn_mfma_f32_16x16x32_bf16(ah, bh2, acc[2], 0, 0, 0);
        acc[3] = __builtin_amdgcn_mfma_f32_16x16x32_bf16(ah, bh3, acc[3], 0, 0, 0);
        acc[4] = __builtin_amdgcn_mfma_f32_16x16x32_bf16(ah, bh4, acc[4], 0, 0, 0);
        __builtin_amdgcn_s_setprio(0);
    }

#pragma unroll
    for (int f = 0; f < 5; ++f)
#pragma unroll
        for (int j = 0; j < 4; ++j)
            red[wk][nh * 5 + f][g * 4 + j][l15 ^ g] = acc[f][j];
    __syncthreads();

    const int fh = tid >> 8, m = (tid >> 4) & 15, n = tid & 15;
    const int row = brow + m;
    const int nn = n ^ (m >> 2);
    const float sx = sqx[row];
    float best = 3.4e38f; int bi = 0;
#pragma unroll
    for (int f = 0; f < 5; ++f) {
        const int fg = fh * 5 + f;
        float d = red[0][fg][m][nn] + red[1][fg][m][nn] +
                  red[2][fg][m][nn] + red[3][fg][m][nn];
        float dv = sx + sqp[fg * 16 + n] - 2.f * d;
        dist[(size_t)row * P_ + fg * 16 + n] = dv;
        float mn = dv;
        mn = fminf(mn, __shfl_xor(mn, 1));
        mn = fminf(mn, __shfl_xor(mn, 2));
        mn = fminf(mn, __shfl_xor(mn, 4));
        mn = fminf(mn, __shfl_xor(mn, 8));
        if (mn < best) { best = mn; bi = fg; }   // strict '<' => first min
    }
    if (n == 0) { cminv[m][fh] = best; cmini[m][fh] = bi; }
    __syncthreads();
    if (tid < 16) {
        float v0 = cminv[tid][0], v1 = cminv[tid][1];
        pred[brow + tid] = (float)((v1 < v0) ? cmini[tid][1] : cmini[tid][0]);
    }
}

// ---- tier-1 fallbacks ----------------------------------------------------

__global__ __launch_bounds__(256)
void k_z_sqx(const float* __restrict__ x, const float* __restrict__ om,
             float* __restrict__ sqx) {
    const int brow = blockIdx.x * 128;
    const int bcol = blockIdx.y * 128;
    __shared__ __align__(16) ushort_t sA[128 * 32];
    __shared__ __align__(16) ushort_t sB[128 * 32];
    const int tid = threadIdx.x;
    const int lane = tid & 63, w = tid >> 6;
    const int wr = (w >> 1) * 64, wc = (w & 1) * 64;
    const int l15 = lane & 15, g = lane >> 4;
    f32x4 acc[4][4] = {};
    for (int k0 = 0; k0 < F_; k0 += 32) {
        __syncthreads();
#pragma unroll
        for (int j = 0; j < 4; ++j) {
            int idx = tid + j * 256;
            int row = idx >> 3, c4 = idx & 7;
            float4 va = *reinterpret_cast<const float4*>(x  + (size_t)(brow + row) * F_ + k0 + c4 * 4);
            float4 vb = *reinterpret_cast<const float4*>(om + (size_t)(bcol + row) * F_ + k0 + c4 * 4);
            int off = (row * 64 + c4 * 8) ^ ((row & 7) << 4);
            *reinterpret_cast<uint2*>(reinterpret_cast<char*>(sA) + off) =
                make_uint2(pk2(va.x, va.y), pk2(va.z, va.w));
            *reinterpret_cast<uint2*>(reinterpret_cast<char*>(sB) + off) =
                make_uint2(pk2(vb.x, vb.y), pk2(vb.z, vb.w));
        }
        __syncthreads();
        short8 a[4], b[4];
#pragma unroll
        for (int m = 0; m < 4; ++m) {
            int row = wr + m * 16 + l15;
            int off = (row * 64 + g * 16) ^ ((row & 7) << 4);
            a[m] = *reinterpret_cast<const short8*>(reinterpret_cast<const char*>(sA) + off);
        }
#pragma unroll
        for (int n = 0; n < 4; ++n) {
            int row = wc + n * 16 + l15;
            int off = (row * 64 + g * 16) ^ ((row & 7) << 4);
            b[n] = *reinterpret_cast<const short8*>(reinterpret_cast<const char*>(sB) + off);
        }
#pragma unroll
        for (int m = 0; m < 4; ++m)
#pragma unroll
            for (int n = 0; n < 4; ++n)
                acc[m][n] = __builtin_amdgcn_mfma_f32_16x16x32_bf16(a[m], b[n], acc[m][n], 0, 0, 0);
    }
#pragma unroll
    for (int m = 0; m < 4; ++m) {
#pragma unroll
        for (int j = 0; j < 4; ++j) {
            float s = 0.f;
#pragma unroll
            for (int n = 0; n < 4; ++n) { float v = acc[m][n][j]; s = fmaf(v, v, s); }
            s += __shfl_xor(s, 1); s += __shfl_xor(s, 2);
            s += __shfl_xor(s, 4); s += __shfl_xor(s, 8);
            if (l15 == 0) atomicAdd(&sqx[brow + wr + m * 16 + g * 4 + j], s);
        }
    }
}

__global__ __launch_bounds__(256)
void k_dist2(const float* __restrict__ x, const ushort_t* __restrict__ uh,
             const float* __restrict__ sqx, const float* __restrict__ sqp,
             float* __restrict__ dist, float* __restrict__ pred) {
    const int brow = blockIdx.x * 16;
    const int tid = threadIdx.x, lane = tid & 63, w = tid >> 6;
    const int l15 = lane & 15, g = lane >> 4;
    __shared__ float red[4][10][16][16];

    f32x4 acc[10] = {};
    const float* xp = x + (size_t)(brow + l15) * F_ + w * 256 + g * 8;
    const ushort_t* buh = uh + (size_t)l15 * F_ + w * 256 + g * 8;

#pragma unroll 2
    for (int ks = 0; ks < 8; ++ks) {
        float4 v0 = *reinterpret_cast<const float4*>(xp + ks * 32);
        float4 v1 = *reinterpret_cast<const float4*>(xp + ks * 32 + 4);
        union { unsigned u[4]; short8 s; } cva;
        cva.u[0] = pk2(v0.x, v0.y); cva.u[1] = pk2(v0.z, v0.w);
        cva.u[2] = pk2(v1.x, v1.y); cva.u[3] = pk2(v1.z, v1.w);
        short8 ah = cva.s;
#pragma unroll
        for (int f = 0; f < 10; ++f) {
            short8 bh = *reinterpret_cast<const short8*>(buh + (size_t)f * 16 * F_ + ks * 32);
            acc[f] = __builtin_amdgcn_mfma_f32_16x16x32_bf16(ah, bh, acc[f], 0, 0, 0);
        }
    }
#pragma unroll
    for (int f = 0; f < 10; ++f)
#pragma unroll
        for (int j = 0; j < 4; ++j) red[w][f][g * 4 + j][l15 ^ g] = acc[f][j];
    __syncthreads();
    const int m = tid >> 4, n = tid & 15;
    const int row = brow + m;
    const int nn = n ^ (m >> 2);
    float sx = sqx[row];
    float best = 3.4e38f; int bi = 0;
#pragma unroll
    for (int f = 0; f < 10; ++f) {
        float d = red[0][f][m][nn] + red[1][f][m][nn] + red[2][f][m][nn] + red[3][f][m][nn];
        float dv = sx + sqp[f * 16 + n] - 2.f * d;
        dist[(size_t)row * P_ + f * 16 + n] = dv;
        float mn = dv;
        mn = fminf(mn, __shfl_xor(mn, 1));
        mn = fminf(mn, __shfl_xor(mn, 2));
        mn = fminf(mn, __shfl_xor(mn, 4));
        mn = fminf(mn, __shfl_xor(mn, 8));
        if (mn < best) { best = mn; bi = f; }
    }
    if (n == 0) pred[row] = (float)bi;
}

// ---- tier-0 fallback kernels (R3 path) -----------------------------------

__global__ __launch_bounds__(256)
void k_proj(const float* __restrict__ prot, const float* __restrict__ om,
            float* __restrict__ zp, float* __restrict__ sqp) {
    const int n0 = blockIdx.x * 16;
    const int tid = threadIdx.x, lane = tid & 63, w = tid >> 6;
    const int l15 = lane & 15, g = lane >> 4;
    __shared__ float red[4][10][16][16];
    f32x4 acc[10] = {};
    const float* op = om   + (size_t)(n0 + l15) * F_ + w * 256 + g * 8;
    const float* pp = prot + (size_t)l15 * F_ + w * 256 + g * 8;
#pragma unroll 2
    for (int ks = 0; ks < 8; ++ks) {
        float4 b0 = *reinterpret_cast<const float4*>(op + ks * 32);
        float4 b1 = *reinterpret_cast<const float4*>(op + ks * 32 + 4);
        union { unsigned u[4]; short8 s; } cbh, cbl;
        cbh.u[0] = pk2(b0.x, b0.y); cbh.u[1] = pk2(b0.z, b0.w);
        cbh.u[2] = pk2(b1.x, b1.y); cbh.u[3] = pk2(b1.z, b1.w);
        cbl.u[0] = pk2(b0.x - lo_f(cbh.u[0]), b0.y - hi_f(cbh.u[0]));
        cbl.u[1] = pk2(b0.z - lo_f(cbh.u[1]), b0.w - hi_f(cbh.u[1]));
        cbl.u[2] = pk2(b1.x - lo_f(cbh.u[2]), b1.y - hi_f(cbh.u[2]));
        cbl.u[3] = pk2(b1.z - lo_f(cbh.u[3]), b1.w - hi_f(cbh.u[3]));
        short8 bh = cbh.s, bl = cbl.s;
#pragma unroll
        for (int f = 0; f < 10; ++f) {
            float4 a0 = *reinterpret_cast<const float4*>(pp + (size_t)f * 16 * F_ + ks * 32);
            float4 a1 = *reinterpret_cast<const float4*>(pp + (size_t)f * 16 * F_ + ks * 32 + 4);
            union { unsigned u[4]; short8 s; } cah, cal;
            cah.u[0] = pk2(a0.x, a0.y); cah.u[1] = pk2(a0.z, a0.w);
            cah.u[2] = pk2(a1.x, a1.y); cah.u[3] = pk2(a1.z, a1.w);
            cal.u[0] = pk2(a0.x - lo_f(cah.u[0]), a0.y - hi_f(cah.u[0]));
            cal.u[1] = pk2(a0.z - lo_f(cah.u[1]), a0.w - hi_f(cah.u[1]));
            cal.u[2] = pk2(a1.x - lo_f(cah.u[2]), a1.y - hi_f(cah.u[2]));
            cal.u[3] = pk2(a1.z - lo_f(cah.u[3]), a1.w - hi_f(cah.u[3]));
            acc[f] = __builtin_amdgcn_mfma_f32_16x16x32_bf16(cah.s, bh, acc[f], 0, 0, 0);
            acc[f] = __builtin_amdgcn_mfma_f32_16x16x32_bf16(cal.s, bh, acc[f], 0, 0, 0);
            acc[f] = __builtin_amdgcn_mfma_f32_16x16x32_bf16(cah.s, bl, acc[f], 0, 0, 0);
        }
    }
#pragma unroll
    for (int f = 0; f < 10; ++f)
#pragma unroll
        for (int j = 0; j < 4; ++j) red[w][f][g * 4 + j][l15] = acc[f][j];
    __syncthreads();
    if (tid < 160) {
        const int f = tid >> 4, m = tid & 15;
        float s = 0.f;
#pragma unroll
        for (int n = 0; n < 16; ++n) {
            float v = red[0][f][m][n] + red[1][f][m][n] + red[2][f][m][n] + red[3][f][m][n];
            zp[(size_t)tid * F_ + n0 + n] = v;
            s = fmaf(v, v, s);
        }
        atomicAdd(&sqp[tid], s);
    }
}

__global__ __launch_bounds__(128)
void k_u(const float* __restrict__ zp, const float* __restrict__ om,
         float* __restrict__ u) {
    const int c  = blockIdx.x * 128 + threadIdx.x;
    const int r0 = blockIdx.y * 32;
    const int kz = blockIdx.z * 128;
    __shared__ __align__(16) float zt[128][36];
    for (int i = threadIdx.x; i < 128 * 32; i += 128) {
        int k = i >> 5, r = i & 31;
        zt[k][r] = zp[(size_t)(r0 + r) * F_ + kz + k];
    }
    __syncthreads();
    float acc[32];
#pragma unroll
    for (int r = 0; r < 32; ++r) acc[r] = 0.f;
    for (int k = 0; k < 128; ++k) {
        float o = om[(size_t)(kz + k) * F_ + c];
        const float4* zr = reinterpret_cast<const float4*>(&zt[k][0]);
#pragma unroll
        for (int r4 = 0; r4 < 8; ++r4) {
            float4 z4 = zr[r4];
            acc[r4 * 4 + 0] = fmaf(z4.x, o, acc[r4 * 4 + 0]);
            acc[r4 * 4 + 1] = fmaf(z4.y, o, acc[r4 * 4 + 1]);
            acc[r4 * 4 + 2] = fmaf(z4.z, o, acc[r4 * 4 + 2]);
            acc[r4 * 4 + 3] = fmaf(z4.w, o, acc[r4 * 4 + 3]);
        }
    }
#pragma unroll
    for (int r = 0; r < 32; ++r) atomicAdd(&u[(size_t)(r0 + r) * F_ + c], acc[r]);
}

__global__ __launch_bounds__(256)
void k_usplit(const float* __restrict__ u, ushort_t* __restrict__ uh) {
    const int b = blockIdx.x, t = threadIdx.x;
    float4 v = *reinterpret_cast<const float4*>(u + (size_t)b * F_ + t * 4);
    unsigned h0 = pk2(v.x, v.y), h1 = pk2(v.z, v.w);
    *reinterpret_cast<uint2*>(uh + (size_t)b * F_ + t * 4) = make_uint2(h0, h1);
}

// ---- launch --------------------------------------------------------------

extern "C" void kernel_launch(void* const* d_in, const int* in_sizes, int n_in,
                              void* d_out, int out_size, void* d_ws, size_t ws_size,
                              hipStream_t stream) {
    (void)in_sizes; (void)n_in; (void)out_size;
    const float* x    = (const float*)d_in[0];
    const float* prot = (const float*)d_in[1];
    const float* om   = (const float*)d_in[2];

    float* out  = (float*)d_out;
    float* dist = out;
    float* pred = out + (size_t)B_ * P_;

    char* W = (char*)d_ws;
    float* sqx = (float*)W;                    // 32768 B
    float* sqp = (float*)(W + 32768);          // 1024 B
    size_t o = 33792;
    ushort_t* phl   = (ushort_t*)(W + o); o += 327680;
    ushort_t* pll   = (ushort_t*)(W + o); o += 327680;
    ushort_t* zph   = (ushort_t*)(W + o); o += 327680;
    ushort_t* zpl   = (ushort_t*)(W + o); o += 327680;
    ushort_t* uh    = (ushort_t*)(W + o); o += 327680;
    ushort_t* up    = (ushort_t*)(W + o); o += 327680;    // packed u
    ushort_t* omh_r = (ushort_t*)(W + o); o += 2097152;
    ushort_t* oml_r = (ushort_t*)(W + o); o += 2097152;
    ushort_t* omTh  = (ushort_t*)(W + o); o += 2097152;
    ushort_t* omTl  = (ushort_t*)(W + o); o += 2097152;
    ushort_t* omh_sw= (ushort_t*)(W + o); o += 2097152;   // ~12.49 MB so far
    ushort_t* xh    = (ushort_t*)(W + o);                 // +16 MB -> ~29.3 MB

    const int tier = (ws_size >= (size_t)30 * 1024 * 1024) ? 2
                   : (ws_size >= (size_t)13 * 1024 * 1024) ? 1 : 0;

    if (tier == 2) {
        // 4 launches: prep(om/prot/zero) -> {zp | x-cvt} -> {u | sq_x} -> dist
        k_prep1<<<267, 256, 0, stream>>>(om, prot, omh_r, oml_r, omTh, omTl,
                                         omh_sw, phl, pll, (float4*)W);
        k_zp2x <<<160 + 4096, 256, 0, stream>>>(phl, pll, omh_r, oml_r,
                                                zph, zpl, sqp, x, xh);
        k_u2z  <<<160 + 512, 256, 0, stream>>>(zph, zpl, omTh, omTl, uh, up,
                                               xh, omh_sw, sqx);
        k_dist5<<<512, 512, 0, stream>>>(xh, up, sqx, sqp, dist, pred);
    } else if (tier == 1) {
        k_prep1<<<267, 256, 0, stream>>>(om, prot, omh_r, oml_r, omTh, omTl,
                                         omh_sw, phl, pll, (float4*)W);
        k_zp2x <<<160, 256, 0, stream>>>(phl, pll, omh_r, oml_r,
                                         zph, zpl, sqp, x, xh);
        k_u2z  <<<160, 256, 0, stream>>>(zph, zpl, omTh, omTl, uh, up,
                                         xh, omh_sw, sqx);
        k_z_sqx<<<dim3(64, 8), 256, 0, stream>>>(x, om, sqx);
        k_dist2<<<512, 256, 0, stream>>>(x, uh, sqx, sqp, dist, pred);
    } else {
        float* wsf = (float*)d_ws;
        float* zp  = wsf + 8448;
        float* u   = wsf + 172288;
        ushort_t* uh0 = (ushort_t*)(wsf + 8448);
        hipMemsetAsync(wsf, 0, 33792, stream);
        hipMemsetAsync(u, 0, (size_t)P_ * F_ * sizeof(float), stream);
        k_proj  <<<64, 256, 0, stream>>>(prot, om, zp, sqp);
        k_u     <<<dim3(8, 5, 8), 128, 0, stream>>>(zp, om, u);
        k_usplit<<<160, 256, 0, stream>>>(u, uh0);
        k_z_sqx <<<dim3(64, 8), 256, 0, stream>>>(x, om, sqx);
        k_dist2 <<<512, 256, 0, stream>>>(x, uh0, sqx, sqp, dist, pred);
    }
}